// Round 1
// baseline (14808.957 us; speedup 1.0000x reference)
//
#include <hip/hip_runtime.h>
#include <stdint.h>

#define NB 16
#define WIN 168
#define NSTEPS 24

typedef __attribute__((ext_vector_type(8))) short bf16x8;
typedef __attribute__((ext_vector_type(4))) float f32x4;

__device__ __forceinline__ short bf_hi(float f){
  uint32_t u = __builtin_bit_cast(uint32_t, f);
  uint32_t r = (u + 0x7FFFu + ((u >> 16) & 1u)) >> 16;
  return (short)r;
}
__device__ __forceinline__ float bf_f(short s){
  uint32_t u = ((uint32_t)(uint16_t)s) << 16;
  return __builtin_bit_cast(float, u);
}
__device__ __forceinline__ void split2(float f, short& hi, short& lo){
  hi = bf_hi(f);
  lo = bf_hi(f - bf_f(hi));
}
__device__ __forceinline__ float sigm(float x){ return 1.0f / (1.0f + __expf(-x)); }
__device__ __forceinline__ float tanh_(float x){
  float e = __expf(-2.0f * fabsf(x));
  float r = (1.0f - e) / (1.0f + e);
  return x < 0.0f ? -r : r;
}
__device__ __forceinline__ f32x4 mfma16(bf16x8 a, bf16x8 b, f32x4 c){
  return __builtin_amdgcn_mfma_f32_16x16x32_bf16(a, b, c, 0, 0, 0);
}

__global__ __launch_bounds__(256, 1) void lstm_rec_kernel(
  const float* __restrict__ x,    const float* __restrict__ Wih1, const float* __restrict__ Whh1,
  const float* __restrict__ bih1, const float* __restrict__ bhh1,
  const float* __restrict__ Wih2, const float* __restrict__ Whh2,
  const float* __restrict__ bih2, const float* __restrict__ bhh2,
  const float* __restrict__ fc1w, const float* __restrict__ fc1b,
  const float* __restrict__ fc2w, const float* __restrict__ fc2b,
  float* __restrict__ out)
{
  // h fragments in B-operand layout: [buf][hi/lo][ktile][quad][batch][jj], bf16 as short
  __shared__ __align__(16) short h1f[2][2][2][4][16][8];  // LSTM1 state (pass A) / LSTM2 state (pass B)
  __shared__ __align__(16) short r1f[2][2][2][4][16][8];  // LSTM1 replay state (pass B)
  __shared__ __align__(16) short rlf[2][2][4][16][8];     // relu(h1(t)) for LSTM2 input
  __shared__ float win_s[WIN][NB];
  __shared__ float Hlast[NB][64];
  __shared__ float fc1w_s[64*68];
  __shared__ float dval_s[NB];

  const int tid = threadIdx.x;
  const int wv  = tid >> 6;    // wave 0..3
  const int ln  = tid & 63;
  const int q   = ln >> 4;     // quad
  const int n   = ln & 15;     // batch col / A-row
  const int bg0 = blockIdx.x * NB;

  // ---- stage window, fc weights, d values
  for (int i = tid; i < WIN*NB; i += 256){ int t = i / NB, b = i % NB; win_s[t][b] = x[(bg0 + b)*169 + t]; }
  for (int i = tid; i < 64*65; i += 256){ int j = i / 65, k = i % 65; fc1w_s[j*68 + k] = fc1w[i]; }
  if (tid < NB) dval_s[tid] = x[(bg0 + tid)*169 + 168];

  const float fc1b_r = fc1b[ln];
  const float fc2w_r = fc2w[ln];
  const float fc2b_r = fc2b[0];
  const short ONE = 0x3F80;   // 1.0 in bf16

  // ---- A-fragment preload (persistent registers).
  // wave wv takes M-tiles (4e+wv): gate j = 64e + 16wv + m, so each lane owns i,f,g,o of the same units.
  bf16x8 A1hi[4][2], A1lo[4][2], Ain1[4];
  bf16x8 A2hi[4][4], A2lo[4][4], Ab2[4];
  #pragma unroll
  for (int e = 0; e < 4; e++){
    const int j = 64*e + 16*wv + n;   // A-frag row m = lane&15
    #pragma unroll
    for (int kt = 0; kt < 2; kt++){
      const float* p = Whh1 + j*64 + kt*32 + q*8;
      #pragma unroll
      for (int jj = 0; jj < 8; jj++){ short h,l; split2(p[jj], h, l); A1hi[e][kt][jj] = h; A1lo[e][kt][jj] = l; }
    }
    #pragma unroll
    for (int kt = 0; kt < 4; kt++){
      const float* p = (kt < 2 ? (Wih2 + j*64 + kt*32) : (Whh2 + j*64 + (kt-2)*32)) + q*8;
      #pragma unroll
      for (int jj = 0; jj < 8; jj++){ short h,l; split2(p[jj], h, l); A2hi[e][kt][jj] = h; A2lo[e][kt][jj] = l; }
    }
    // input/bias tile for LSTM1: k-rows pair with B rows (win_hi, win_lo, win_hi, 1, 1)
    bf16x8 ain = {0,0,0,0,0,0,0,0};
    bf16x8 ab2 = {0,0,0,0,0,0,0,0};
    if (q == 0){
      short wh, wl; split2(Wih1[j], wh, wl);
      short bh, bl; split2(bih1[j] + bhh1[j], bh, bl);
      ain[0] = wh; ain[1] = wh; ain[2] = wl; ain[3] = bh; ain[4] = bl;
      short b2h, b2l; split2(bih2[j] + bhh2[j], b2h, b2l);
      ab2[0] = b2h; ab2[1] = b2l;
    }
    Ain1[e] = ain; Ab2[e] = ab2;
  }
  bf16x8 bb2 = {0,0,0,0,0,0,0,0};
  if (q == 0){ bb2[0] = ONE; bb2[1] = ONE; }

  float c1[4], c2[4], c1r[4];

  for (int s = 0; s < NSTEPS; s++){
    // zero h1 frag buf0 (initial h1 = 0)
    { int* p = (int*)&h1f[0][0][0][0][0][0];
      #pragma unroll
      for (int i = 0; i < 4; i++) p[tid + 256*i] = 0; }
    #pragma unroll
    for (int r = 0; r < 4; r++) c1[r] = 0.0f;

    // ================= pass A: LSTM1, keep final (h1,c1) =================
    for (int t = 0; t < WIN; t++){
      __syncthreads();
      const int rb = t & 1, wb = rb ^ 1;
      const int slot = (s + t) % WIN;
      bf16x8 Bh[2], Bl[2];
      #pragma unroll
      for (int kt = 0; kt < 2; kt++){
        Bh[kt] = *(const bf16x8*)&h1f[rb][0][kt][q][n][0];
        Bl[kt] = *(const bf16x8*)&h1f[rb][1][kt][q][n][0];
      }
      bf16x8 bin = {0,0,0,0,0,0,0,0};
      { float wval = win_s[slot][n]; short h,l; split2(wval, h, l);
        if (q == 0){ bin[0]=h; bin[1]=l; bin[2]=h; bin[3]=ONE; bin[4]=ONE; } }
      f32x4 acc[4];
      #pragma unroll
      for (int e = 0; e < 4; e++){
        f32x4 a = {0.f,0.f,0.f,0.f};
        #pragma unroll
        for (int kt = 0; kt < 2; kt++){
          a = mfma16(A1hi[e][kt], Bh[kt], a);
          a = mfma16(A1hi[e][kt], Bl[kt], a);
          a = mfma16(A1lo[e][kt], Bh[kt], a);
        }
        a = mfma16(Ain1[e], bin, a);
        acc[e] = a;
      }
      #pragma unroll
      for (int r = 0; r < 4; r++){
        float gi = acc[0][r], gf = acc[1][r], gg = acc[2][r], go = acc[3][r];
        float cn = sigm(gf)*c1[r] + sigm(gi)*tanh_(gg);
        c1[r] = cn;
        float hn = sigm(go)*tanh_(cn);
        const int u = 16*wv + 4*q + r;
        const int kt = u >> 5, q2 = (u >> 3) & 3, jj = u & 7;
        short hh, hl; split2(hn, hh, hl);
        h1f[wb][0][kt][q2][n][jj] = hh;
        h1f[wb][1][kt][q2][n][jj] = hl;
      }
    }

    // ================= pass B: LSTM1 replay + LSTM2 =================
    #pragma unroll
    for (int r = 0; r < 4; r++){ c2[r] = c1[r]; c1r[r] = 0.0f; }
    { int* p = (int*)&r1f[0][0][0][0][0][0];
      #pragma unroll
      for (int i = 0; i < 4; i++) p[tid + 256*i] = 0; }

    for (int t = 0; t < WIN; t++){
      __syncthreads();
      const int rb = t & 1, wb = rb ^ 1;
      const int slot = (s + t) % WIN;
      // ---- LSTM1 replay (regenerates relu(h1(t)) without global scratch)
      {
        bf16x8 Bh[2], Bl[2];
        #pragma unroll
        for (int kt = 0; kt < 2; kt++){
          Bh[kt] = *(const bf16x8*)&r1f[rb][0][kt][q][n][0];
          Bl[kt] = *(const bf16x8*)&r1f[rb][1][kt][q][n][0];
        }
        bf16x8 bin = {0,0,0,0,0,0,0,0};
        { float wval = win_s[slot][n]; short h,l; split2(wval, h, l);
          if (q == 0){ bin[0]=h; bin[1]=l; bin[2]=h; bin[3]=ONE; bin[4]=ONE; } }
        f32x4 acc[4];
        #pragma unroll
        for (int e = 0; e < 4; e++){
          f32x4 a = {0.f,0.f,0.f,0.f};
          #pragma unroll
          for (int kt = 0; kt < 2; kt++){
            a = mfma16(A1hi[e][kt], Bh[kt], a);
            a = mfma16(A1hi[e][kt], Bl[kt], a);
            a = mfma16(A1lo[e][kt], Bh[kt], a);
          }
          a = mfma16(Ain1[e], bin, a);
          acc[e] = a;
        }
        #pragma unroll
        for (int r = 0; r < 4; r++){
          float gi = acc[0][r], gf = acc[1][r], gg = acc[2][r], go = acc[3][r];
          float cn = sigm(gf)*c1r[r] + sigm(gi)*tanh_(gg);
          c1r[r] = cn;
          float hn = sigm(go)*tanh_(cn);
          const int u = 16*wv + 4*q + r;
          const int kt = u >> 5, q2 = (u >> 3) & 3, jj = u & 7;
          short hh, hl; split2(hn, hh, hl);
          r1f[wb][0][kt][q2][n][jj] = hh;
          r1f[wb][1][kt][q2][n][jj] = hl;
          float rl = fmaxf(hn, 0.0f);
          split2(rl, hh, hl);
          rlf[0][kt][q2][n][jj] = hh;
          rlf[1][kt][q2][n][jj] = hl;
        }
      }
      __syncthreads();
      // ---- LSTM2: K = [relu(h1(t)) (kt0,1) | h2(t-1) (kt2,3)] + bias tile
      {
        bf16x8 B1h[2], B1l[2], B2h[2], B2l[2];
        #pragma unroll
        for (int kt = 0; kt < 2; kt++){
          B1h[kt] = *(const bf16x8*)&rlf[0][kt][q][n][0];
          B1l[kt] = *(const bf16x8*)&rlf[1][kt][q][n][0];
          B2h[kt] = *(const bf16x8*)&h1f[rb][0][kt][q][n][0];
          B2l[kt] = *(const bf16x8*)&h1f[rb][1][kt][q][n][0];
        }
        f32x4 acc[4];
        #pragma unroll
        for (int e = 0; e < 4; e++){
          f32x4 a = {0.f,0.f,0.f,0.f};
          #pragma unroll
          for (int kt = 0; kt < 2; kt++){
            a = mfma16(A2hi[e][kt], B1h[kt], a);
            a = mfma16(A2hi[e][kt], B1l[kt], a);
            a = mfma16(A2lo[e][kt], B1h[kt], a);
          }
          #pragma unroll
          for (int kt = 0; kt < 2; kt++){
            a = mfma16(A2hi[e][kt+2], B2h[kt], a);
            a = mfma16(A2hi[e][kt+2], B2l[kt], a);
            a = mfma16(A2lo[e][kt+2], B2h[kt], a);
          }
          a = mfma16(Ab2[e], bb2, a);
          acc[e] = a;
        }
        #pragma unroll
        for (int r = 0; r < 4; r++){
          float gi = acc[0][r], gf = acc[1][r], gg = acc[2][r], go = acc[3][r];
          float cn = sigm(gf)*c2[r] + sigm(gi)*tanh_(gg);
          c2[r] = cn;
          float hn = sigm(go)*tanh_(cn);
          const int u = 16*wv + 4*q + r;
          const int kt = u >> 5, q2 = (u >> 3) & 3, jj = u & 7;
          short hh, hl; split2(hn, hh, hl);
          h1f[wb][0][kt][q2][n][jj] = hh;
          h1f[wb][1][kt][q2][n][jj] = hl;
          if (t == WIN-1) Hlast[n][u] = fmaxf(hn, 0.0f);
        }
      }
    }
    __syncthreads();

    // ================= FC head: wave wv -> batches 4wv..4wv+3, lane = fc1 row =================
    float o4[4];
    #pragma unroll
    for (int bi = 0; bi < 4; bi++){
      const int b = 4*wv + bi;
      float a1 = fc1b_r;
      #pragma unroll
      for (int k4 = 0; k4 < 16; k4++){
        const float* wp = &fc1w_s[ln*68 + k4*4];
        const float* hp = &Hlast[b][k4*4];
        a1 += wp[0]*hp[0] + wp[1]*hp[1] + wp[2]*hp[2] + wp[3]*hp[3];
      }
      a1 += dval_s[b] * fc1w_s[ln*68 + 64];     // d term (feat[64])
      float v = a1 * fc2w_r;
      #pragma unroll
      for (int off = 32; off > 0; off >>= 1) v += __shfl_xor(v, off);
      o4[bi] = v + fc2b_r;
    }
    if (ln == 0){
      #pragma unroll
      for (int bi = 0; bi < 4; bi++){
        const int b = 4*wv + bi;
        out[(bg0 + b)*24 + s] = o4[bi];
        win_s[s % WIN][b] = o4[bi];   // append prediction to circular window
      }
    }
    // next outer's first __syncthreads orders win_s write vs reads
  }
}

extern "C" void kernel_launch(void* const* d_in, const int* in_sizes, int n_in,
                              void* d_out, int out_size, void* d_ws, size_t ws_size,
                              hipStream_t stream) {
  (void)in_sizes; (void)n_in; (void)d_ws; (void)ws_size; (void)out_size;
  lstm_rec_kernel<<<dim3(4096/NB), dim3(256), 0, stream>>>(
      (const float*)d_in[0], (const float*)d_in[1], (const float*)d_in[2],
      (const float*)d_in[3], (const float*)d_in[4], (const float*)d_in[5],
      (const float*)d_in[6], (const float*)d_in[7], (const float*)d_in[8],
      (const float*)d_in[9], (const float*)d_in[10], (const float*)d_in[11],
      (const float*)d_in[12], (float*)d_out);
}

// Round 2
// 8144.542 us; speedup vs baseline: 1.8183x; 1.8183x over previous
//
#include <hip/hip_runtime.h>
#include <stdint.h>

#define NB 16
#define WIN 168
#define NSTEPS 24

typedef __attribute__((ext_vector_type(8))) short bf16x8;
typedef __attribute__((ext_vector_type(4))) float f32x4;

#if __has_builtin(__builtin_amdgcn_rcpf)
#define RCPF(x) __builtin_amdgcn_rcpf(x)
#else
#define RCPF(x) (1.0f / (x))
#endif
#if __has_builtin(__builtin_amdgcn_exp2f)
#define EXP2F(x) __builtin_amdgcn_exp2f(x)
#else
#define EXP2F(x) __expf((x) * 0.6931471805599453f)
#endif

__device__ __forceinline__ float sigm(float x){
  return RCPF(1.0f + EXP2F(x * -1.4426950408889634f));
}
__device__ __forceinline__ float tanh_(float x){
  return __builtin_fmaf(2.0f, RCPF(1.0f + EXP2F(x * -2.8853900817779268f)), -1.0f);
}

__device__ __forceinline__ uint32_t bf_rn(float f){
  uint32_t u = __builtin_bit_cast(uint32_t, f);
  return (u + 0x7FFFu + ((u >> 16) & 1u)) >> 16;
}
__device__ __forceinline__ float bf_f(uint32_t s){
  return __builtin_bit_cast(float, s << 16);
}
// truncate-to-bf16 hi + round-nearest lo; |f-(hi+lo)| <= 2^-17 |f|
__device__ __forceinline__ void split_t(float f, uint32_t& hi, uint32_t& lo){
  uint32_t u = __builtin_bit_cast(uint32_t, f);
  hi = u >> 16;
  lo = bf_rn(f - bf_f(hi));
}
// round-nearest both (weight preload, one-time)
__device__ __forceinline__ void split_s(float f, short& hi, short& lo){
  uint32_t h = bf_rn(f);
  hi = (short)h;
  lo = (short)bf_rn(f - bf_f(h));
}
__device__ __forceinline__ f32x4 mfma16(bf16x8 a, bf16x8 b, f32x4 c){
  return __builtin_amdgcn_mfma_f32_16x16x32_bf16(a, b, c, 0, 0, 0);
}

__device__ __forceinline__ void lstm_epi(const f32x4 acc[4], float c[4], float hn[4]){
  #pragma unroll
  for (int r = 0; r < 4; r++){
    float gi = acc[0][r], gf = acc[1][r], gg = acc[2][r], go = acc[3][r];
    float cn = __builtin_fmaf(sigm(gf), c[r], sigm(gi) * tanh_(gg));
    c[r] = cn;
    hn[r] = sigm(go) * tanh_(cn);
  }
}

__global__ __launch_bounds__(256, 1) void lstm_rec_kernel(
  const float* __restrict__ x,    const float* __restrict__ Wih1, const float* __restrict__ Whh1,
  const float* __restrict__ bih1, const float* __restrict__ bhh1,
  const float* __restrict__ Wih2, const float* __restrict__ Whh2,
  const float* __restrict__ bih2, const float* __restrict__ bhh2,
  const float* __restrict__ fc1w, const float* __restrict__ fc1b,
  const float* __restrict__ fc2w, const float* __restrict__ fc2b,
  float* __restrict__ out)
{
  // h fragments in B-operand layout: [buf][hi/lo][ktile][quad][batch][jj]
  __shared__ __align__(16) short h1f[2][2][2][4][16][8];  // LSTM1 state (pass A) / LSTM2 state (pass B)
  __shared__ __align__(16) short r1f[2][2][2][4][16][8];  // LSTM1 replay state (pass B)
  __shared__ __align__(16) short rlf[2][2][2][4][16][8];  // relu(h1(t)) double-buffered
  __shared__ float win_s[WIN][NB];
  __shared__ float Hlast[NB][64];
  __shared__ float fc1w_s[64*68];
  __shared__ float dval_s[NB];

  const int tid = threadIdx.x;
  const int wv  = tid >> 6;
  const int ln  = tid & 63;
  const int q   = ln >> 4;
  const int n   = ln & 15;
  const int bg0 = blockIdx.x * NB;
  const int u0  = 16*wv + 4*q;          // first of this lane's 4 units
  const int kt_  = u0 >> 5;             // write-side frag coords (loop-invariant)
  const int q2_  = (u0 >> 3) & 3;
  const int jj0_ = u0 & 7;              // in {0,4} -> 8B-aligned b64 writes

  // ---- stage window, fc weights, d values
  for (int i = tid; i < WIN*NB; i += 256){ int t = i >> 4, b = i & 15; win_s[t][b] = x[(bg0 + b)*169 + t]; }
  for (int i = tid; i < 64*65; i += 256){ int j = i / 65, k = i % 65; fc1w_s[j*68 + k] = fc1w[i]; }
  if (tid < NB) dval_s[tid] = x[(bg0 + tid)*169 + 168];

  const float fc1b_r = fc1b[ln];
  const float fc2w_r = fc2w[ln];
  const float fc2b_r = fc2b[0];

  // ---- A-fragment preload. Wave wv owns gate rows j = 64e + 16wv + m.
  bf16x8 A1hi[4][2], A1lo[4][2], Ain1[4];
  bf16x8 A2hi[4][4], A2lo[4][4];
  f32x4 b1c[4], b2c[4];                 // biases as MFMA C-init
  #pragma unroll
  for (int e = 0; e < 4; e++){
    const int ja = 64*e + 16*wv + n;    // A-row m = lane&15
    #pragma unroll
    for (int kt = 0; kt < 2; kt++){
      const float* p = Whh1 + ja*64 + kt*32 + q*8;
      #pragma unroll
      for (int jj = 0; jj < 8; jj++){ short h,l; split_s(p[jj], h, l); A1hi[e][kt][jj] = h; A1lo[e][kt][jj] = l; }
    }
    #pragma unroll
    for (int kt = 0; kt < 4; kt++){
      const float* p = (kt < 2 ? (Wih2 + ja*64 + kt*32) : (Whh2 + ja*64 + (kt-2)*32)) + q*8;
      #pragma unroll
      for (int jj = 0; jj < 8; jj++){ short h,l; split_s(p[jj], h, l); A2hi[e][kt][jj] = h; A2lo[e][kt][jj] = l; }
    }
    bf16x8 ain = {0,0,0,0,0,0,0,0};
    if (q == 0){ short wh, wl; split_s(Wih1[ja], wh, wl); ain[0] = wh; ain[1] = wh; ain[2] = wl; }
    Ain1[e] = ain;
    const int jc = 64*e + u0;           // C-row gate index for this lane
    #pragma unroll
    for (int r = 0; r < 4; r++){
      b1c[e][r] = bih1[jc+r] + bhh1[jc+r];
      b2c[e][r] = bih2[jc+r] + bhh2[jc+r];
    }
  }

  float c1[4], c2[4], c1r[4];

  // ---------- lambdas (inlined) ----------
  auto lstm1_step = [&](short (&st)[2][2][2][4][16][8], float* cst, int rb, int wb, int slot, bool relu_out){
    bf16x8 Bh0 = *(const bf16x8*)&st[rb][0][0][q][n][0];
    bf16x8 Bl0 = *(const bf16x8*)&st[rb][1][0][q][n][0];
    bf16x8 Bh1 = *(const bf16x8*)&st[rb][0][1][q][n][0];
    bf16x8 Bl1 = *(const bf16x8*)&st[rb][1][1][q][n][0];
    bf16x8 bin = {0,0,0,0,0,0,0,0};
    { float xv = win_s[slot][n]; uint32_t xh, xl; split_t(xv, xh, xl);
      if (q == 0){ bin[0] = (short)xh; bin[1] = (short)xl; bin[2] = (short)xh; } }
    f32x4 acc[4];
    #pragma unroll
    for (int e = 0; e < 4; e++){
      f32x4 a = b1c[e];
      a = mfma16(A1hi[e][0], Bh0, a);
      a = mfma16(A1hi[e][0], Bl0, a);
      a = mfma16(A1lo[e][0], Bh0, a);
      a = mfma16(A1hi[e][1], Bh1, a);
      a = mfma16(A1hi[e][1], Bl1, a);
      a = mfma16(A1lo[e][1], Bh1, a);
      a = mfma16(Ain1[e], bin, a);
      acc[e] = a;
    }
    float hn[4];
    lstm_epi(acc, cst, hn);
    uint32_t ph[4], pl[4];
    #pragma unroll
    for (int r = 0; r < 4; r++) split_t(hn[r], ph[r], pl[r]);
    *(uint2*)&st[wb][0][kt_][q2_][n][jj0_] = make_uint2(ph[0] | (ph[1]<<16), ph[2] | (ph[3]<<16));
    *(uint2*)&st[wb][1][kt_][q2_][n][jj0_] = make_uint2(pl[0] | (pl[1]<<16), pl[2] | (pl[3]<<16));
    if (relu_out){
      uint32_t sh[4], sl[4];
      #pragma unroll
      for (int r = 0; r < 4; r++){ bool pos = hn[r] > 0.0f; sh[r] = pos ? ph[r] : 0u; sl[r] = pos ? pl[r] : 0u; }
      *(uint2*)&rlf[rb][0][kt_][q2_][n][jj0_] = make_uint2(sh[0] | (sh[1]<<16), sh[2] | (sh[3]<<16));
      *(uint2*)&rlf[rb][1][kt_][q2_][n][jj0_] = make_uint2(sl[0] | (sl[1]<<16), sl[2] | (sl[3]<<16));
    }
  };

  auto lstm2_step = [&](int rbuf, int wbuf, bool last){
    bf16x8 L1h0 = *(const bf16x8*)&rlf[rbuf][0][0][q][n][0];
    bf16x8 L1l0 = *(const bf16x8*)&rlf[rbuf][1][0][q][n][0];
    bf16x8 L1h1 = *(const bf16x8*)&rlf[rbuf][0][1][q][n][0];
    bf16x8 L1l1 = *(const bf16x8*)&rlf[rbuf][1][1][q][n][0];
    bf16x8 L2h0 = *(const bf16x8*)&h1f[rbuf][0][0][q][n][0];
    bf16x8 L2l0 = *(const bf16x8*)&h1f[rbuf][1][0][q][n][0];
    bf16x8 L2h1 = *(const bf16x8*)&h1f[rbuf][0][1][q][n][0];
    bf16x8 L2l1 = *(const bf16x8*)&h1f[rbuf][1][1][q][n][0];
    f32x4 acc[4];
    #pragma unroll
    for (int e = 0; e < 4; e++){
      f32x4 a = b2c[e];
      a = mfma16(A2hi[e][0], L1h0, a);
      a = mfma16(A2hi[e][0], L1l0, a);
      a = mfma16(A2lo[e][0], L1h0, a);
      a = mfma16(A2hi[e][1], L1h1, a);
      a = mfma16(A2hi[e][1], L1l1, a);
      a = mfma16(A2lo[e][1], L1h1, a);
      a = mfma16(A2hi[e][2], L2h0, a);
      a = mfma16(A2hi[e][2], L2l0, a);
      a = mfma16(A2lo[e][2], L2h0, a);
      a = mfma16(A2hi[e][3], L2h1, a);
      a = mfma16(A2hi[e][3], L2l1, a);
      a = mfma16(A2lo[e][3], L2h1, a);
      acc[e] = a;
    }
    float hn[4];
    lstm_epi(acc, c2, hn);
    if (!last){
      uint32_t ph[4], pl[4];
      #pragma unroll
      for (int r = 0; r < 4; r++) split_t(hn[r], ph[r], pl[r]);
      *(uint2*)&h1f[wbuf][0][kt_][q2_][n][jj0_] = make_uint2(ph[0] | (ph[1]<<16), ph[2] | (ph[3]<<16));
      *(uint2*)&h1f[wbuf][1][kt_][q2_][n][jj0_] = make_uint2(pl[0] | (pl[1]<<16), pl[2] | (pl[3]<<16));
    } else {
      #pragma unroll
      for (int r = 0; r < 4; r++) Hlast[n][u0 + r] = fmaxf(hn[r], 0.0f);
    }
  };

  // ---------- outer recursion ----------
  for (int s = 0; s < NSTEPS; s++){
    // zero h1 frag buf0 (initial h1 = 0)
    { int* p = (int*)&h1f[0][0][0][0][0][0];
      #pragma unroll
      for (int i = 0; i < 4; i++) p[tid + 256*i] = 0; }
    #pragma unroll
    for (int r = 0; r < 4; r++) c1[r] = 0.0f;

    // ===== pass A: LSTM1, keep final (h1,c1); final h lands in h1f buf0 =====
    int slot = s;
    for (int t = 0; t < WIN; t++){
      __syncthreads();
      lstm1_step(h1f, c1, t & 1, (t & 1) ^ 1, slot, false);
      slot++; if (slot == WIN) slot = 0;
    }

    // ===== pass B: pipelined LSTM1-replay(i) + LSTM2(i-1), 1 barrier/iter =====
    #pragma unroll
    for (int r = 0; r < 4; r++){ c2[r] = c1[r]; c1r[r] = 0.0f; }
    { int* p = (int*)&r1f[0][0][0][0][0][0];
      #pragma unroll
      for (int i = 0; i < 4; i++) p[tid + 256*i] = 0; }

    slot = s;
    __syncthreads();
    lstm1_step(r1f, c1r, 0, 1, slot, true);          // replay(0)
    slot++;
    for (int i = 1; i < WIN; i++){
      __syncthreads();
      const int rb = i & 1, wb = rb ^ 1;
      lstm1_step(r1f, c1r, rb, wb, slot, true);      // replay(i): r1f[rb]->r1f[wb], rlf[rb]
      lstm2_step(wb, rb, false);                     // LSTM2(i-1): rlf[wb],h1f[wb] -> h1f[rb]
      slot++; if (slot == WIN) slot = 0;
    }
    __syncthreads();
    lstm2_step((WIN - 1) & 1, 0, true);              // LSTM2(WIN-1) -> Hlast
    __syncthreads();

    // ===== FC head: wave wv -> batches 4wv..4wv+3, lane = fc1 row =====
    float o4[4];
    #pragma unroll
    for (int bi = 0; bi < 4; bi++){
      const int b = 4*wv + bi;
      float a1 = fc1b_r;
      #pragma unroll
      for (int k4 = 0; k4 < 16; k4++){
        const float* wp = &fc1w_s[ln*68 + k4*4];
        const float* hp = &Hlast[b][k4*4];
        a1 += wp[0]*hp[0] + wp[1]*hp[1] + wp[2]*hp[2] + wp[3]*hp[3];
      }
      a1 += dval_s[b] * fc1w_s[ln*68 + 64];
      float v = a1 * fc2w_r;
      #pragma unroll
      for (int off = 32; off > 0; off >>= 1) v += __shfl_xor(v, off);
      o4[bi] = v + fc2b_r;
    }
    if (ln == 0){
      #pragma unroll
      for (int bi = 0; bi < 4; bi++){
        const int b = 4*wv + bi;
        out[(bg0 + b)*24 + s] = o4[bi];
        win_s[s % WIN][b] = o4[bi];    // append prediction to circular window
      }
    }
    // next pass A's first __syncthreads orders win_s write vs reads
  }
}

extern "C" void kernel_launch(void* const* d_in, const int* in_sizes, int n_in,
                              void* d_out, int out_size, void* d_ws, size_t ws_size,
                              hipStream_t stream) {
  (void)in_sizes; (void)n_in; (void)d_ws; (void)ws_size; (void)out_size;
  lstm_rec_kernel<<<dim3(4096/NB), dim3(256), 0, stream>>>(
      (const float*)d_in[0], (const float*)d_in[1], (const float*)d_in[2],
      (const float*)d_in[3], (const float*)d_in[4], (const float*)d_in[5],
      (const float*)d_in[6], (const float*)d_in[7], (const float*)d_in[8],
      (const float*)d_in[9], (const float*)d_in[10], (const float*)d_in[11],
      (const float*)d_in[12], (float*)d_out);
}

// Round 4
// 5761.175 us; speedup vs baseline: 2.5705x; 1.4137x over previous
//
#include <hip/hip_runtime.h>
#include <stdint.h>

#define NB 16
#define WIN 168
#define NSTEPS 24
#define NBLK (4096/NB)

typedef __attribute__((ext_vector_type(8))) short bf16x8;
typedef __attribute__((ext_vector_type(4))) float f32x4;

#if __has_builtin(__builtin_amdgcn_rcpf)
#define RCPF(x) __builtin_amdgcn_rcpf(x)
#else
#define RCPF(x) (1.0f / (x))
#endif
#if __has_builtin(__builtin_amdgcn_exp2f)
#define EXP2F(x) __builtin_amdgcn_exp2f(x)
#else
#define EXP2F(x) __expf((x) * 0.6931471805599453f)
#endif

// ---- activation formulas FROZEN at R2 versions (absmax 2.44e-4, 13.5x margin).
// R3's fused sigtanh is banned until separately exonerated.
__device__ __forceinline__ float sigm(float x){
  return RCPF(1.0f + EXP2F(x * -1.4426950408889634f));
}
__device__ __forceinline__ float tanh_(float x){
  return __builtin_fmaf(2.0f, RCPF(1.0f + EXP2F(x * -2.8853900817779268f)), -1.0f);
}

__device__ __forceinline__ uint32_t bf_rn(float f){
  uint32_t u = __builtin_bit_cast(uint32_t, f);
  return (u + 0x7FFFu + ((u >> 16) & 1u)) >> 16;
}
__device__ __forceinline__ float bf_f(uint32_t s){
  return __builtin_bit_cast(float, s << 16);
}
// truncate-to-bf16 hi + round-nearest lo
__device__ __forceinline__ void split_t(float f, uint32_t& hi, uint32_t& lo){
  uint32_t u = __builtin_bit_cast(uint32_t, f);
  hi = u >> 16;
  lo = bf_rn(f - bf_f(hi));
}
// round-nearest both (weight preload, one-time)
__device__ __forceinline__ void split_s(float f, short& hi, short& lo){
  uint32_t h = bf_rn(f);
  hi = (short)h;
  lo = (short)bf_rn(f - bf_f(h));
}
__device__ __forceinline__ f32x4 mfma16(bf16x8 a, bf16x8 b, f32x4 c){
  return __builtin_amdgcn_mfma_f32_16x16x32_bf16(a, b, c, 0, 0, 0);
}

__device__ __forceinline__ void lstm_epi(const f32x4 acc[4], float c[4], float hn[4]){
  #pragma unroll
  for (int r = 0; r < 4; r++){
    float gi = acc[0][r], gf = acc[1][r], gg = acc[2][r], go = acc[3][r];
    float cn = __builtin_fmaf(sigm(gf), c[r], sigm(gi) * tanh_(gg));
    c[r] = cn;
    hn[r] = sigm(go) * tanh_(cn);
  }
}

// LDS frag block: per (hl,kt): 4 q2-rows of 136 shorts (128 data + 8 pad = 272B stride)
#define FROW 136
#define FBLK 544           // 4*136 shorts per (hl,kt) block
#define FB(buf,hl,kt) ((((buf)*2 + (hl))*2 + (kt)) * FBLK)
// one state buffer (buf) = 4 blocks = 4*FBLK shorts = 2*FBLK ints
#define BUF_INTS (2*FBLK)

template<bool USE_WS>
__global__ __launch_bounds__(256, 1) void lstm_rec_kernel(
  const float* __restrict__ x,    const float* __restrict__ Wih1, const float* __restrict__ Whh1,
  const float* __restrict__ bih1, const float* __restrict__ bhh1,
  const float* __restrict__ Wih2, const float* __restrict__ Whh2,
  const float* __restrict__ bih2, const float* __restrict__ bhh2,
  const float* __restrict__ fc1w, const float* __restrict__ fc1b,
  const float* __restrict__ fc2w, const float* __restrict__ fc2b,
  float* __restrict__ out, short* __restrict__ hist)
{
  __shared__ __align__(16) short h1f[2*2*2*FBLK];                    // LSTM1 (A) / LSTM2 (B) state
  __shared__ __align__(16) short r1f[USE_WS ? 16 : 2*2*2*FBLK];      // fallback: replay state
  __shared__ __align__(16) short rlf[USE_WS ? 16 : 2*2*2*FBLK];      // fallback: relu(h1) dbuf
  __shared__ float win_s[WIN][NB];
  __shared__ float Hlast[NB][68];
  __shared__ float fc1w_s[64*68];
  __shared__ float dval_s[NB];

  const int tid = threadIdx.x;
  const int wv  = tid >> 6;
  const int ln  = tid & 63;
  const int q   = ln >> 4;
  const int n   = ln & 15;
  const int bg0 = blockIdx.x * NB;
  const int u0  = 16*wv + 4*q;
  const int kt_  = u0 >> 5;
  const int q2_  = (u0 >> 3) & 3;
  const int jj0_ = u0 & 7;                    // {0,4}
  const int rdo  = q*FROW + n*8;              // frag read offset (shorts)
  const int wro  = q2_*FROW + n*8 + jj0_;     // frag write offset (shorts)
  const int gwo  = kt_*512 + q2_*128 + n*8 + jj0_;  // hist write offset
  short* __restrict__ hblk = USE_WS ? (hist + (size_t)blockIdx.x * WIN * 2048) : nullptr;

  for (int i = tid; i < WIN*NB; i += 256){ int t = i >> 4, b = i & 15; win_s[t][b] = x[(bg0 + b)*169 + t]; }
  for (int i = tid; i < 64*65; i += 256){ int j = i / 65, k = i % 65; fc1w_s[j*68 + k] = fc1w[i]; }
  if (tid < NB) dval_s[tid] = x[(bg0 + tid)*169 + 168];

  const float fc1b_r = fc1b[ln];
  const float fc2w_r = fc2w[ln];
  const float fc2b_r = fc2b[0];

  // ---- persistent A-fragments. Wave wv owns gate rows j = 64e + 16wv + m.
  bf16x8 A1hi[4][2], A1lo[4][2], Ain1[4];
  bf16x8 A2hi[4][4], A2lo[4][4];
  f32x4 b1c[4], b2c[4];
  #pragma unroll
  for (int e = 0; e < 4; e++){
    const int ja = 64*e + 16*wv + n;
    #pragma unroll
    for (int kt = 0; kt < 2; kt++){
      const float* p = Whh1 + ja*64 + kt*32 + q*8;
      #pragma unroll
      for (int jj = 0; jj < 8; jj++){ short h,l; split_s(p[jj], h, l); A1hi[e][kt][jj] = h; A1lo[e][kt][jj] = l; }
    }
    #pragma unroll
    for (int kt = 0; kt < 4; kt++){
      const float* p = (kt < 2 ? (Wih2 + ja*64 + kt*32) : (Whh2 + ja*64 + (kt-2)*32)) + q*8;
      #pragma unroll
      for (int jj = 0; jj < 8; jj++){ short h,l; split_s(p[jj], h, l); A2hi[e][kt][jj] = h; A2lo[e][kt][jj] = l; }
    }
    bf16x8 ain = {0,0,0,0,0,0,0,0};
    if (q == 0){ short wh, wl; split_s(Wih1[ja], wh, wl); ain[0] = wh; ain[1] = wh; ain[2] = wl; }
    Ain1[e] = ain;
    const int jc = 64*e + u0;
    #pragma unroll
    for (int r = 0; r < 4; r++){
      b1c[e][r] = bih1[jc+r] + bhh1[jc+r];
      b2c[e][r] = bih2[jc+r] + bhh2[jc+r];
    }
  }

  float c1[4], c2[4], c1r[4];

  // relu_dst: 0 = none, 1 = global hist (USE_WS), 2 = rlf LDS (fallback)
  auto lstm1_step = [&](short* S, float* cst, int rb, int wb, int slot, int relu_dst, int t){
    bf16x8 Bh0 = *(const bf16x8*)&S[FB(rb,0,0)+rdo];
    bf16x8 Bl0 = *(const bf16x8*)&S[FB(rb,1,0)+rdo];
    bf16x8 Bh1 = *(const bf16x8*)&S[FB(rb,0,1)+rdo];
    bf16x8 Bl1 = *(const bf16x8*)&S[FB(rb,1,1)+rdo];
    bf16x8 bin = {0,0,0,0,0,0,0,0};
    { float xv = win_s[slot][n]; uint32_t xh, xl; split_t(xv, xh, xl);
      if (q == 0){ bin[0] = (short)xh; bin[1] = (short)xl; bin[2] = (short)xh; } }
    f32x4 acc[4];
    #pragma unroll
    for (int e = 0; e < 4; e++){
      f32x4 a = b1c[e];
      a = mfma16(A1hi[e][0], Bh0, a);
      a = mfma16(A1hi[e][0], Bl0, a);
      a = mfma16(A1lo[e][0], Bh0, a);
      a = mfma16(A1hi[e][1], Bh1, a);
      a = mfma16(A1hi[e][1], Bl1, a);
      a = mfma16(A1lo[e][1], Bh1, a);
      a = mfma16(Ain1[e], bin, a);
      acc[e] = a;
    }
    float hn[4];
    lstm_epi(acc, cst, hn);
    uint32_t ph[4], pl[4];
    #pragma unroll
    for (int r = 0; r < 4; r++) split_t(hn[r], ph[r], pl[r]);
    *(uint2*)&S[FB(wb,0,kt_)+wro] = make_uint2(ph[0] | (ph[1]<<16), ph[2] | (ph[3]<<16));
    *(uint2*)&S[FB(wb,1,kt_)+wro] = make_uint2(pl[0] | (pl[1]<<16), pl[2] | (pl[3]<<16));
    if (relu_dst){
      uint32_t sh[4], sl[4];
      #pragma unroll
      for (int r = 0; r < 4; r++){ bool pos = hn[r] > 0.0f; sh[r] = pos ? ph[r] : 0u; sl[r] = pos ? pl[r] : 0u; }
      uint2 phi = make_uint2(sh[0] | (sh[1]<<16), sh[2] | (sh[3]<<16));
      uint2 plo = make_uint2(sl[0] | (sl[1]<<16), sl[2] | (sl[3]<<16));
      if (relu_dst == 1){
        short* Hp = hblk + (size_t)t * 2048;
        *(uint2*)&Hp[gwo]        = phi;
        *(uint2*)&Hp[1024 + gwo] = plo;
      } else {
        *(uint2*)&rlf[FB(rb,0,kt_)+wro] = phi;
        *(uint2*)&rlf[FB(rb,1,kt_)+wro] = plo;
      }
    }
  };

  // LSTM2 step; L1 input either from regs (USE_WS) or rlf LDS (fallback)
  auto lstm2_core = [&](bf16x8 L1h0, bf16x8 L1l0, bf16x8 L1h1, bf16x8 L1l1, int rbuf, int wbuf, bool last){
    bf16x8 L2h0 = *(const bf16x8*)&h1f[FB(rbuf,0,0)+rdo];
    bf16x8 L2l0 = *(const bf16x8*)&h1f[FB(rbuf,1,0)+rdo];
    bf16x8 L2h1 = *(const bf16x8*)&h1f[FB(rbuf,0,1)+rdo];
    bf16x8 L2l1 = *(const bf16x8*)&h1f[FB(rbuf,1,1)+rdo];
    f32x4 acc[4];
    #pragma unroll
    for (int e = 0; e < 4; e++){
      f32x4 a = b2c[e];
      a = mfma16(A2hi[e][0], L1h0, a);
      a = mfma16(A2hi[e][0], L1l0, a);
      a = mfma16(A2lo[e][0], L1h0, a);
      a = mfma16(A2hi[e][1], L1h1, a);
      a = mfma16(A2hi[e][1], L1l1, a);
      a = mfma16(A2lo[e][1], L1h1, a);
      a = mfma16(A2hi[e][2], L2h0, a);
      a = mfma16(A2hi[e][2], L2l0, a);
      a = mfma16(A2lo[e][2], L2h0, a);
      a = mfma16(A2hi[e][3], L2h1, a);
      a = mfma16(A2hi[e][3], L2l1, a);
      a = mfma16(A2lo[e][3], L2h1, a);
      acc[e] = a;
    }
    float hn[4];
    lstm_epi(acc, c2, hn);
    if (!last){
      uint32_t ph[4], pl[4];
      #pragma unroll
      for (int r = 0; r < 4; r++) split_t(hn[r], ph[r], pl[r]);
      *(uint2*)&h1f[FB(wbuf,0,kt_)+wro] = make_uint2(ph[0] | (ph[1]<<16), ph[2] | (ph[3]<<16));
      *(uint2*)&h1f[FB(wbuf,1,kt_)+wro] = make_uint2(pl[0] | (pl[1]<<16), pl[2] | (pl[3]<<16));
    } else {
      #pragma unroll
      for (int r = 0; r < 4; r++) Hlast[n][u0 + r] = fmaxf(hn[r], 0.0f);
    }
  };

  for (int s = 0; s < NSTEPS; s++){
    // zero ALL of h1f buf0 (hi AND lo halves): 4*FBLK shorts = BUF_INTS ints.
    // R3 bug: only half was zeroed -> stale lo-parts leaked into the recursion.
    { int* p = (int*)&h1f[0];
      for (int i = tid; i < BUF_INTS; i += 256) p[i] = 0; }
    #pragma unroll
    for (int r = 0; r < 4; r++) c1[r] = 0.0f;

    // ===== pass A: LSTM1 (relu(h1(t)) streamed to hist when USE_WS) =====
    int slot = s;
    for (int t = 0; t < WIN; t++){
      __syncthreads();
      lstm1_step(h1f, c1, t & 1, (t & 1) ^ 1, slot, USE_WS ? 1 : 0, t);
      slot++; if (slot == WIN) slot = 0;
    }
    // h1 final is in h1f buf0 (t=167 wrote wb=0); c1 holds c-final

    #pragma unroll
    for (int r = 0; r < 4; r++) c2[r] = c1[r];

    if constexpr (USE_WS) {
      // ===== pass B: LSTM2 only, relu(h1) streamed from hist with 1-step prefetch =====
      const int ro = q*128 + n*8;
      bf16x8 ch0 = *(const bf16x8*)&hblk[ro];
      bf16x8 cl0 = *(const bf16x8*)&hblk[1024 + ro];
      bf16x8 ch1 = *(const bf16x8*)&hblk[512 + ro];
      bf16x8 cl1 = *(const bf16x8*)&hblk[1536 + ro];
      for (int t = 0; t < WIN; t++){
        bf16x8 nh0, nl0, nh1, nl1;
        if (t < WIN-1){
          const short* Hp = hblk + (size_t)(t+1) * 2048;
          nh0 = *(const bf16x8*)&Hp[ro];
          nl0 = *(const bf16x8*)&Hp[1024 + ro];
          nh1 = *(const bf16x8*)&Hp[512 + ro];
          nl1 = *(const bf16x8*)&Hp[1536 + ro];
        }
        __syncthreads();
        lstm2_core(ch0, cl0, ch1, cl1, t & 1, (t & 1) ^ 1, t == WIN-1);
        ch0 = nh0; cl0 = nl0; ch1 = nh1; cl1 = nl1;
      }
    } else {
      // ===== fallback: pipelined replay + LSTM2 (R2 scheme) =====
      #pragma unroll
      for (int r = 0; r < 4; r++) c1r[r] = 0.0f;
      { int* p = (int*)&r1f[0];
        for (int i = tid; i < BUF_INTS; i += 256) p[i] = 0; }
      slot = s;
      __syncthreads();
      lstm1_step(r1f, c1r, 0, 1, slot, 2, 0);
      slot++;
      for (int i = 1; i < WIN; i++){
        __syncthreads();
        const int rb = i & 1, wb = rb ^ 1;
        lstm1_step(r1f, c1r, rb, wb, slot, 2, i);
        bf16x8 L1h0 = *(const bf16x8*)&rlf[FB(wb,0,0)+rdo];
        bf16x8 L1l0 = *(const bf16x8*)&rlf[FB(wb,1,0)+rdo];
        bf16x8 L1h1 = *(const bf16x8*)&rlf[FB(wb,0,1)+rdo];
        bf16x8 L1l1 = *(const bf16x8*)&rlf[FB(wb,1,1)+rdo];
        lstm2_core(L1h0, L1l0, L1h1, L1l1, wb, rb, false);
        slot++; if (slot == WIN) slot = 0;
      }
      __syncthreads();
      {
        const int rb = (WIN - 1) & 1;
        bf16x8 L1h0 = *(const bf16x8*)&rlf[FB(rb,0,0)+rdo];
        bf16x8 L1l0 = *(const bf16x8*)&rlf[FB(rb,1,0)+rdo];
        bf16x8 L1h1 = *(const bf16x8*)&rlf[FB(rb,0,1)+rdo];
        bf16x8 L1l1 = *(const bf16x8*)&rlf[FB(rb,1,1)+rdo];
        lstm2_core(L1h0, L1l0, L1h1, L1l1, rb, 0, true);
      }
    }
    __syncthreads();

    // ===== FC head =====
    float o4[4];
    #pragma unroll
    for (int bi = 0; bi < 4; bi++){
      const int b = 4*wv + bi;
      float a1 = fc1b_r;
      #pragma unroll
      for (int k4 = 0; k4 < 16; k4++){
        const float* wp = &fc1w_s[ln*68 + k4*4];
        const float* hp = &Hlast[b][k4*4];
        a1 += wp[0]*hp[0] + wp[1]*hp[1] + wp[2]*hp[2] + wp[3]*hp[3];
      }
      a1 += dval_s[b] * fc1w_s[ln*68 + 64];
      float v = a1 * fc2w_r;
      #pragma unroll
      for (int off = 32; off > 0; off >>= 1) v += __shfl_xor(v, off);
      o4[bi] = v + fc2b_r;
    }
    if (ln == 0){
      #pragma unroll
      for (int bi = 0; bi < 4; bi++){
        const int b = 4*wv + bi;
        out[(bg0 + b)*24 + s] = o4[bi];
        win_s[s % WIN][b] = o4[bi];
      }
    }
  }
}

extern "C" void kernel_launch(void* const* d_in, const int* in_sizes, int n_in,
                              void* d_out, int out_size, void* d_ws, size_t ws_size,
                              hipStream_t stream) {
  (void)in_sizes; (void)n_in; (void)out_size;
  const size_t need = (size_t)NBLK * WIN * 2048 * sizeof(short);   // ~168 MB
  if (ws_size >= need){
    lstm_rec_kernel<true><<<dim3(NBLK), dim3(256), 0, stream>>>(
        (const float*)d_in[0], (const float*)d_in[1], (const float*)d_in[2],
        (const float*)d_in[3], (const float*)d_in[4], (const float*)d_in[5],
        (const float*)d_in[6], (const float*)d_in[7], (const float*)d_in[8],
        (const float*)d_in[9], (const float*)d_in[10], (const float*)d_in[11],
        (const float*)d_in[12], (float*)d_out, (short*)d_ws);
  } else {
    lstm_rec_kernel<false><<<dim3(NBLK), dim3(256), 0, stream>>>(
        (const float*)d_in[0], (const float*)d_in[1], (const float*)d_in[2],
        (const float*)d_in[3], (const float*)d_in[4], (const float*)d_in[5],
        (const float*)d_in[6], (const float*)d_in[7], (const float*)d_in[8],
        (const float*)d_in[9], (const float*)d_in[10], (const float*)d_in[11],
        (const float*)d_in[12], (float*)d_out, (short*)nullptr);
  }
}

// Round 5
// 5478.130 us; speedup vs baseline: 2.7033x; 1.0517x over previous
//
#include <hip/hip_runtime.h>
#include <stdint.h>

#define NB 16
#define WIN 168
#define NSTEPS 24
#define NBLK (4096/NB)

typedef __attribute__((ext_vector_type(8))) short bf16x8;
typedef __attribute__((ext_vector_type(4))) float f32x4;

#if __has_builtin(__builtin_amdgcn_rcpf)
#define RCPF(x) __builtin_amdgcn_rcpf(x)
#else
#define RCPF(x) (1.0f / (x))
#endif
#if __has_builtin(__builtin_amdgcn_exp2f)
#define EXP2F(x) __builtin_amdgcn_exp2f(x)
#else
#define EXP2F(x) __expf((x) * 0.6931471805599453f)
#endif

// ---- activation formulas FROZEN at R2 versions (absmax 2.441e-4, 13.5x margin).
__device__ __forceinline__ float sigm(float x){
  return RCPF(1.0f + EXP2F(x * -1.4426950408889634f));
}
__device__ __forceinline__ float tanh_(float x){
  return __builtin_fmaf(2.0f, RCPF(1.0f + EXP2F(x * -2.8853900817779268f)), -1.0f);
}

__device__ __forceinline__ uint32_t bf_rn(float f){
  uint32_t u = __builtin_bit_cast(uint32_t, f);
  return (u + 0x7FFFu + ((u >> 16) & 1u)) >> 16;
}
__device__ __forceinline__ float bf_f(uint32_t s){
  return __builtin_bit_cast(float, s << 16);
}
// truncate-to-bf16 hi + round-nearest lo
__device__ __forceinline__ void split_t(float f, uint32_t& hi, uint32_t& lo){
  uint32_t u = __builtin_bit_cast(uint32_t, f);
  hi = u >> 16;
  lo = bf_rn(f - bf_f(hi));
}
// round-nearest both (weight preload, one-time)
__device__ __forceinline__ void split_s(float f, short& hi, short& lo){
  uint32_t h = bf_rn(f);
  hi = (short)h;
  lo = (short)bf_rn(f - bf_f(h));
}
__device__ __forceinline__ f32x4 mfma16(bf16x8 a, bf16x8 b, f32x4 c){
  return __builtin_amdgcn_mfma_f32_16x16x32_bf16(a, b, c, 0, 0, 0);
}

__device__ __forceinline__ void lstm_epi(const f32x4 acc[4], float c[4], float hn[4]){
  #pragma unroll
  for (int r = 0; r < 4; r++){
    float gi = acc[0][r], gf = acc[1][r], gg = acc[2][r], go = acc[3][r];
    float cn = __builtin_fmaf(sigm(gf), c[r], sigm(gi) * tanh_(gg));
    c[r] = cn;
    hn[r] = sigm(go) * tanh_(cn);
  }
}

// LDS frag block: per (hl,kt): 4 q2-rows of 136 shorts (128 data + 8 pad)
#define FROW 136
#define FBLK 544
#define FB(buf,hl,kt) ((((buf)*2 + (hl))*2 + (kt)) * FBLK)
#define BUF_INTS (2*FBLK)

// FUSED: interleave LSTM1(outer s+1) with LSTM2(outer s); requires ws for hist.
template<bool FUSED>
__global__ __launch_bounds__(256, 1) void lstm_rec_kernel(
  const float* __restrict__ x,    const float* __restrict__ Wih1, const float* __restrict__ Whh1,
  const float* __restrict__ bih1, const float* __restrict__ bhh1,
  const float* __restrict__ Wih2, const float* __restrict__ Whh2,
  const float* __restrict__ bih2, const float* __restrict__ bhh2,
  const float* __restrict__ fc1w, const float* __restrict__ fc1b,
  const float* __restrict__ fc2w, const float* __restrict__ fc2b,
  float* __restrict__ out, short* __restrict__ hist)
{
  __shared__ __align__(16) short aS[2*2*2*FBLK];                   // LSTM1 state dbuf
  __shared__ __align__(16) short bS[FUSED ? 2*2*2*FBLK : 16];      // LSTM2 state dbuf (fused)
  __shared__ __align__(16) short r1f[FUSED ? 16 : 2*2*2*FBLK];     // fallback: replay state
  __shared__ __align__(16) short rlf[FUSED ? 16 : 2*2*2*FBLK];     // fallback: relu(h1) dbuf
  __shared__ float win_s[WIN][NB];
  __shared__ float Hlast[NB][68];
  __shared__ float fc1w_s[64*68];
  __shared__ float dval_s[NB];

  const int tid = threadIdx.x;
  const int wv  = tid >> 6;
  const int ln  = tid & 63;
  const int q   = ln >> 4;
  const int n   = ln & 15;
  const int bg0 = blockIdx.x * NB;
  const int u0  = 16*wv + 4*q;
  const int kt_  = u0 >> 5;
  const int q2_  = (u0 >> 3) & 3;
  const int jj0_ = u0 & 7;                    // {0,4}
  const int rdo  = q*FROW + n*8;              // frag read offset (shorts)
  const int wro  = q2_*FROW + n*8 + jj0_;     // frag write offset (shorts)
  const int gwo  = kt_*512 + q2_*128 + n*8 + jj0_;  // hist write offset
  const int ro   = q*128 + n*8;               // hist read offset
  short* __restrict__ hblk = FUSED ? (hist + (size_t)blockIdx.x * WIN * 2048) : nullptr;

  for (int i = tid; i < WIN*NB; i += 256){ int t = i >> 4, b = i & 15; win_s[t][b] = x[(bg0 + b)*169 + t]; }
  for (int i = tid; i < 64*65; i += 256){ int j = i / 65, k = i % 65; fc1w_s[j*68 + k] = fc1w[i]; }
  if (tid < NB) dval_s[tid] = x[(bg0 + tid)*169 + 168];

  const float fc1b_r = fc1b[ln];
  const float fc2w_r = fc2w[ln];
  const float fc2b_r = fc2b[0];

  // ---- persistent A-fragments. Wave wv owns gate rows j = 64e + 16wv + m.
  bf16x8 A1hi[4][2], A1lo[4][2], Ain1[4];
  bf16x8 A2hi[4][4], A2lo[4][4];
  f32x4 b1c[4], b2c[4];
  #pragma unroll
  for (int e = 0; e < 4; e++){
    const int ja = 64*e + 16*wv + n;
    #pragma unroll
    for (int kt = 0; kt < 2; kt++){
      const float* p = Whh1 + ja*64 + kt*32 + q*8;
      #pragma unroll
      for (int jj = 0; jj < 8; jj++){ short h,l; split_s(p[jj], h, l); A1hi[e][kt][jj] = h; A1lo[e][kt][jj] = l; }
    }
    #pragma unroll
    for (int kt = 0; kt < 4; kt++){
      const float* p = (kt < 2 ? (Wih2 + ja*64 + kt*32) : (Whh2 + ja*64 + (kt-2)*32)) + q*8;
      #pragma unroll
      for (int jj = 0; jj < 8; jj++){ short h,l; split_s(p[jj], h, l); A2hi[e][kt][jj] = h; A2lo[e][kt][jj] = l; }
    }
    bf16x8 ain = {0,0,0,0,0,0,0,0};
    if (q == 0){ short wh, wl; split_s(Wih1[ja], wh, wl); ain[0] = wh; ain[1] = wh; ain[2] = wl; }
    Ain1[e] = ain;
    const int jc = 64*e + u0;
    #pragma unroll
    for (int r = 0; r < 4; r++){
      b1c[e][r] = bih1[jc+r] + bhh1[jc+r];
      b2c[e][r] = bih2[jc+r] + bhh2[jc+r];
    }
  }

  float c1[4], c2[4], c1r[4];

  // relu_dst: 0 none, 1 global hist, 2 rlf LDS. first: t==0, h==0 -> skip h MFMAs.
  auto lstm1_step = [&](short* S, float* cst, int rb, int wb, int slot, int relu_dst, int t, bool first){
    f32x4 acc[4];
    bf16x8 bin = {0,0,0,0,0,0,0,0};
    { float xv = win_s[slot][n]; uint32_t xh, xl; split_t(xv, xh, xl);
      if (q == 0){ bin[0] = (short)xh; bin[1] = (short)xl; bin[2] = (short)xh; } }
    if (first){
      #pragma unroll
      for (int e = 0; e < 4; e++) acc[e] = mfma16(Ain1[e], bin, b1c[e]);
    } else {
      bf16x8 Bh0 = *(const bf16x8*)&S[FB(rb,0,0)+rdo];
      bf16x8 Bl0 = *(const bf16x8*)&S[FB(rb,1,0)+rdo];
      bf16x8 Bh1 = *(const bf16x8*)&S[FB(rb,0,1)+rdo];
      bf16x8 Bl1 = *(const bf16x8*)&S[FB(rb,1,1)+rdo];
      #pragma unroll
      for (int e = 0; e < 4; e++){
        f32x4 a = b1c[e];
        a = mfma16(A1hi[e][0], Bh0, a);
        a = mfma16(A1hi[e][0], Bl0, a);
        a = mfma16(A1lo[e][0], Bh0, a);
        a = mfma16(A1hi[e][1], Bh1, a);
        a = mfma16(A1hi[e][1], Bl1, a);
        a = mfma16(A1lo[e][1], Bh1, a);
        a = mfma16(Ain1[e], bin, a);
        acc[e] = a;
      }
    }
    float hn[4];
    lstm_epi(acc, cst, hn);
    uint32_t ph[4], pl[4];
    #pragma unroll
    for (int r = 0; r < 4; r++) split_t(hn[r], ph[r], pl[r]);
    *(uint2*)&S[FB(wb,0,kt_)+wro] = make_uint2(ph[0] | (ph[1]<<16), ph[2] | (ph[3]<<16));
    *(uint2*)&S[FB(wb,1,kt_)+wro] = make_uint2(pl[0] | (pl[1]<<16), pl[2] | (pl[3]<<16));
    if (relu_dst){
      uint32_t sh[4], sl[4];
      #pragma unroll
      for (int r = 0; r < 4; r++){ bool pos = hn[r] > 0.0f; sh[r] = pos ? ph[r] : 0u; sl[r] = pos ? pl[r] : 0u; }
      uint2 phi = make_uint2(sh[0] | (sh[1]<<16), sh[2] | (sh[3]<<16));
      uint2 plo = make_uint2(sl[0] | (sl[1]<<16), sl[2] | (sl[3]<<16));
      if (relu_dst == 1){
        short* Hp = hblk + (size_t)t * 2048;
        *(uint2*)&Hp[gwo]        = phi;
        *(uint2*)&Hp[1024 + gwo] = plo;
      } else {
        *(uint2*)&rlf[FB(rb,0,kt_)+wro] = phi;
        *(uint2*)&rlf[FB(rb,1,kt_)+wro] = plo;
      }
    }
  };

  // LSTM2 step; recurrent-state read from Sr[rbuf], write to Sw[wbuf].
  auto lstm2_core = [&](bf16x8 L1h0, bf16x8 L1l0, bf16x8 L1h1, bf16x8 L1l1,
                        const short* Sr, int rbuf, short* Sw, int wbuf, bool last){
    bf16x8 L2h0 = *(const bf16x8*)&Sr[FB(rbuf,0,0)+rdo];
    bf16x8 L2l0 = *(const bf16x8*)&Sr[FB(rbuf,1,0)+rdo];
    bf16x8 L2h1 = *(const bf16x8*)&Sr[FB(rbuf,0,1)+rdo];
    bf16x8 L2l1 = *(const bf16x8*)&Sr[FB(rbuf,1,1)+rdo];
    f32x4 acc[4];
    #pragma unroll
    for (int e = 0; e < 4; e++){
      f32x4 a = b2c[e];
      a = mfma16(A2hi[e][0], L1h0, a);
      a = mfma16(A2hi[e][0], L1l0, a);
      a = mfma16(A2lo[e][0], L1h0, a);
      a = mfma16(A2hi[e][1], L1h1, a);
      a = mfma16(A2hi[e][1], L1l1, a);
      a = mfma16(A2lo[e][1], L1h1, a);
      a = mfma16(A2hi[e][2], L2h0, a);
      a = mfma16(A2hi[e][2], L2l0, a);
      a = mfma16(A2lo[e][2], L2h0, a);
      a = mfma16(A2hi[e][3], L2h1, a);
      a = mfma16(A2hi[e][3], L2l1, a);
      a = mfma16(A2lo[e][3], L2h1, a);
      acc[e] = a;
    }
    float hn[4];
    lstm_epi(acc, c2, hn);
    if (!last){
      uint32_t ph[4], pl[4];
      #pragma unroll
      for (int r = 0; r < 4; r++) split_t(hn[r], ph[r], pl[r]);
      *(uint2*)&Sw[FB(wbuf,0,kt_)+wro] = make_uint2(ph[0] | (ph[1]<<16), ph[2] | (ph[3]<<16));
      *(uint2*)&Sw[FB(wbuf,1,kt_)+wro] = make_uint2(pl[0] | (pl[1]<<16), pl[2] | (pl[3]<<16));
    } else {
      #pragma unroll
      for (int r = 0; r < 4; r++) Hlast[n][u0 + r] = fmaxf(hn[r], 0.0f);
    }
  };

  auto hload = [&](int t, bf16x8& h0, bf16x8& l0, bf16x8& h1, bf16x8& l1){
    const short* Hp = hblk + (size_t)t * 2048;
    h0 = *(const bf16x8*)&Hp[ro];
    l0 = *(const bf16x8*)&Hp[1024 + ro];
    h1 = *(const bf16x8*)&Hp[512 + ro];
    l1 = *(const bf16x8*)&Hp[1536 + ro];
  };

  auto fc_head = [&](int s){
    float o4[4];
    #pragma unroll
    for (int bi = 0; bi < 4; bi++){
      const int b = 4*wv + bi;
      float a1 = fc1b_r;
      #pragma unroll
      for (int k4 = 0; k4 < 16; k4++){
        const float* wp = &fc1w_s[ln*68 + k4*4];
        const float* hp = &Hlast[b][k4*4];
        a1 += wp[0]*hp[0] + wp[1]*hp[1] + wp[2]*hp[2] + wp[3]*hp[3];
      }
      a1 += dval_s[b] * fc1w_s[ln*68 + 64];
      float v = a1 * fc2w_r;
      #pragma unroll
      for (int off = 32; off > 0; off >>= 1) v += __shfl_xor(v, off);
      o4[bi] = v + fc2b_r;
    }
    if (ln == 0){
      #pragma unroll
      for (int bi = 0; bi < 4; bi++){
        const int b = 4*wv + bi;
        out[(bg0 + b)*24 + s] = o4[bi];
        win_s[s % WIN][b] = o4[bi];
      }
    }
  };

  if constexpr (FUSED){
    // ===== sweep 0: A(0) alone; writes hist slots 0..167; final h1 -> aS[0] =====
    #pragma unroll
    for (int r = 0; r < 4; r++) c1[r] = 0.0f;
    __syncthreads();
    lstm1_step(aS, c1, 0, 1, 0, 1, 0, true);
    for (int t = 1; t < WIN; t++){
      __syncthreads();
      lstm1_step(aS, c1, t & 1, (t & 1) ^ 1, t, 1, t, false);
    }

    // ===== fused sweeps sg=1..23: A(sg) + B(sg-1) =====
    for (int sg = 1; sg < NSTEPS; sg++){
      #pragma unroll
      for (int r = 0; r < 4; r++){ c2[r] = c1[r]; c1[r] = 0.0f; }
      bf16x8 ch0, cl0, ch1, cl1, nh0, nl0, nh1, nl1;
      hload(0, ch0, cl0, ch1, cl1);
      int slot = sg;                       // (sg+0) % WIN, sg<24<WIN
      // t=0 peeled: A reads no state (h=0), B reads h2-init from aS[0]
      hload(1, nh0, nl0, nh1, nl1);
      __syncthreads();                     // orders prev A(167) aS[0] write + drains hload(0)
      lstm1_step(aS, c1, 0, 1, slot, 1, 0, true);
      lstm2_core(ch0, cl0, ch1, cl1, aS, 0, bS, 1, false);
      ch0 = nh0; cl0 = nl0; ch1 = nh1; cl1 = nl1;
      slot++; if (slot == WIN) slot = 0;
      for (int t = 1; t < WIN-1; t++){
        hload(t+1, nh0, nl0, nh1, nl1);
        __syncthreads();
        lstm1_step(aS, c1, t & 1, (t & 1) ^ 1, slot, 1, t, false);
        lstm2_core(ch0, cl0, ch1, cl1, bS, t & 1, bS, (t & 1) ^ 1, false);
        ch0 = nh0; cl0 = nl0; ch1 = nh1; cl1 = nl1;
        slot++; if (slot == WIN) slot = 0;
      }
      // t=167 special: B -> Hlast; FC produces out(sg-1) into window; then A(167)
      __syncthreads();
      lstm2_core(ch0, cl0, ch1, cl1, bS, 1, bS, 0, true);
      __syncthreads();
      fc_head(sg - 1);
      __syncthreads();
      lstm1_step(aS, c1, 1, 0, slot, 1, WIN-1, false);   // slot == sg-1 (just written by FC)
    }

    // ===== epilogue: B(23) alone =====
    #pragma unroll
    for (int r = 0; r < 4; r++) c2[r] = c1[r];
    {
      bf16x8 ch0, cl0, ch1, cl1, nh0, nl0, nh1, nl1;
      hload(0, ch0, cl0, ch1, cl1);
      hload(1, nh0, nl0, nh1, nl1);
      __syncthreads();                     // orders A(23,167) aS[0] write
      lstm2_core(ch0, cl0, ch1, cl1, aS, 0, bS, 1, false);
      ch0 = nh0; cl0 = nl0; ch1 = nh1; cl1 = nl1;
      for (int t = 1; t < WIN; t++){
        if (t < WIN-1) hload(t+1, nh0, nl0, nh1, nl1);
        __syncthreads();
        lstm2_core(ch0, cl0, ch1, cl1, bS, t & 1, bS, (t & 1) ^ 1, t == WIN-1);
        ch0 = nh0; cl0 = nl0; ch1 = nh1; cl1 = nl1;
      }
      __syncthreads();
      fc_head(NSTEPS - 1);
    }
  } else {
    // ===== fallback (no ws): R4 replay scheme =====
    for (int s = 0; s < NSTEPS; s++){
      { int* p = (int*)&aS[0];
        for (int i = tid; i < BUF_INTS; i += 256) p[i] = 0; }
      #pragma unroll
      for (int r = 0; r < 4; r++) c1[r] = 0.0f;
      int slot = s;
      for (int t = 0; t < WIN; t++){
        __syncthreads();
        lstm1_step(aS, c1, t & 1, (t & 1) ^ 1, slot, 0, t, false);
        slot++; if (slot == WIN) slot = 0;
      }
      #pragma unroll
      for (int r = 0; r < 4; r++){ c2[r] = c1[r]; c1r[r] = 0.0f; }
      { int* p = (int*)&r1f[0];
        for (int i = tid; i < BUF_INTS; i += 256) p[i] = 0; }
      slot = s;
      __syncthreads();
      lstm1_step(r1f, c1r, 0, 1, slot, 2, 0, false);
      slot++;
      for (int i = 1; i < WIN; i++){
        __syncthreads();
        const int rb = i & 1, wb = rb ^ 1;
        lstm1_step(r1f, c1r, rb, wb, slot, 2, i, false);
        bf16x8 L1h0 = *(const bf16x8*)&rlf[FB(wb,0,0)+rdo];
        bf16x8 L1l0 = *(const bf16x8*)&rlf[FB(wb,1,0)+rdo];
        bf16x8 L1h1 = *(const bf16x8*)&rlf[FB(wb,0,1)+rdo];
        bf16x8 L1l1 = *(const bf16x8*)&rlf[FB(wb,1,1)+rdo];
        lstm2_core(L1h0, L1l0, L1h1, L1l1, aS, wb, aS, rb, false);
        slot++; if (slot == WIN) slot = 0;
      }
      __syncthreads();
      {
        const int rb = (WIN - 1) & 1;
        bf16x8 L1h0 = *(const bf16x8*)&rlf[FB(rb,0,0)+rdo];
        bf16x8 L1l0 = *(const bf16x8*)&rlf[FB(rb,1,0)+rdo];
        bf16x8 L1h1 = *(const bf16x8*)&rlf[FB(rb,0,1)+rdo];
        bf16x8 L1l1 = *(const bf16x8*)&rlf[FB(rb,1,1)+rdo];
        lstm2_core(L1h0, L1l0, L1h1, L1l1, aS, rb, aS, 0, true);
      }
      __syncthreads();
      fc_head(s);
    }
  }
}

extern "C" void kernel_launch(void* const* d_in, const int* in_sizes, int n_in,
                              void* d_out, int out_size, void* d_ws, size_t ws_size,
                              hipStream_t stream) {
  (void)in_sizes; (void)n_in; (void)out_size;
  const size_t need = (size_t)NBLK * WIN * 2048 * sizeof(short);   // ~168 MB
  if (ws_size >= need){
    lstm_rec_kernel<true><<<dim3(NBLK), dim3(256), 0, stream>>>(
        (const float*)d_in[0], (const float*)d_in[1], (const float*)d_in[2],
        (const float*)d_in[3], (const float*)d_in[4], (const float*)d_in[5],
        (const float*)d_in[6], (const float*)d_in[7], (const float*)d_in[8],
        (const float*)d_in[9], (const float*)d_in[10], (const float*)d_in[11],
        (const float*)d_in[12], (float*)d_out, (short*)d_ws);
  } else {
    lstm_rec_kernel<false><<<dim3(NBLK), dim3(256), 0, stream>>>(
        (const float*)d_in[0], (const float*)d_in[1], (const float*)d_in[2],
        (const float*)d_in[3], (const float*)d_in[4], (const float*)d_in[5],
        (const float*)d_in[6], (const float*)d_in[7], (const float*)d_in[8],
        (const float*)d_in[9], (const float*)d_in[10], (const float*)d_in[11],
        (const float*)d_in[12], (float*)d_out, (short*)nullptr);
  }
}

// Round 6
// 5020.057 us; speedup vs baseline: 2.9500x; 1.0912x over previous
//
#include <hip/hip_runtime.h>
#include <stdint.h>

#define NB 16
#define WIN 168
#define NSTEPS 24
#define NBLK (4096/NB)
#define NT 512

typedef __attribute__((ext_vector_type(8))) short bf16x8;
typedef __attribute__((ext_vector_type(4))) float f32x4;

#if __has_builtin(__builtin_amdgcn_rcpf)
#define RCPF(x) __builtin_amdgcn_rcpf(x)
#else
#define RCPF(x) (1.0f / (x))
#endif
#if __has_builtin(__builtin_amdgcn_exp2f)
#define EXP2F(x) __builtin_amdgcn_exp2f(x)
#else
#define EXP2F(x) __expf((x) * 0.6931471805599453f)
#endif

// ---- activation formulas FROZEN at R2 versions (absmax 2.441e-4, 13.5x margin).
__device__ __forceinline__ float sigm(float x){
  return RCPF(1.0f + EXP2F(x * -1.4426950408889634f));
}
__device__ __forceinline__ float tanh_(float x){
  return __builtin_fmaf(2.0f, RCPF(1.0f + EXP2F(x * -2.8853900817779268f)), -1.0f);
}

__device__ __forceinline__ uint32_t bf_rn(float f){
  uint32_t u = __builtin_bit_cast(uint32_t, f);
  return (u + 0x7FFFu + ((u >> 16) & 1u)) >> 16;
}
__device__ __forceinline__ float bf_f(uint32_t s){
  return __builtin_bit_cast(float, s << 16);
}
__device__ __forceinline__ void split_t(float f, uint32_t& hi, uint32_t& lo){
  uint32_t u = __builtin_bit_cast(uint32_t, f);
  hi = u >> 16;
  lo = bf_rn(f - bf_f(hi));
}
__device__ __forceinline__ void split_s(float f, short& hi, short& lo){
  uint32_t h = bf_rn(f);
  hi = (short)h;
  lo = (short)bf_rn(f - bf_f(h));
}
__device__ __forceinline__ f32x4 mfma16(bf16x8 a, bf16x8 b, f32x4 c){
  return __builtin_amdgcn_mfma_f32_16x16x32_bf16(a, b, c, 0, 0, 0);
}

__device__ __forceinline__ void lstm_epi(const f32x4 acc[4], float c[4], float hn[4]){
  #pragma unroll
  for (int r = 0; r < 4; r++){
    float gi = acc[0][r], gf = acc[1][r], gg = acc[2][r], go = acc[3][r];
    float cn = __builtin_fmaf(sigm(gf), c[r], sigm(gi) * tanh_(gg));
    c[r] = cn;
    hn[r] = sigm(go) * tanh_(cn);
  }
}

// LDS frag block: per (hl,kt): 4 q2-rows of 136 shorts (128 data + 8 pad)
#define FROW 136
#define FBLK 544
#define FB(buf,hl,kt) ((((buf)*2 + (hl))*2 + (kt)) * FBLK)
#define BUF_INTS (2*FBLK)

// ============================================================================
// FUSED + WAVE-SPECIALIZED kernel: 512 threads; waves 0-3 = LSTM1 (producer,
// streams relu(h1) to hist), waves 4-7 = LSTM2 (consumer). One A-wave + one
// B-wave per SIMD -> 2 waves/SIMD hide each other's latency. Barrier counts
// are matched EXACTLY between the two branches.
// ============================================================================
__global__ __launch_bounds__(NT, 2) void lstm_fused_kernel(
  const float* __restrict__ x,    const float* __restrict__ Wih1, const float* __restrict__ Whh1,
  const float* __restrict__ bih1, const float* __restrict__ bhh1,
  const float* __restrict__ Wih2, const float* __restrict__ Whh2,
  const float* __restrict__ bih2, const float* __restrict__ bhh2,
  const float* __restrict__ fc1w, const float* __restrict__ fc1b,
  const float* __restrict__ fc2w, const float* __restrict__ fc2b,
  float* __restrict__ out, short* __restrict__ hist)
{
  __shared__ __align__(16) short aS[2*2*2*FBLK];   // LSTM1 state dbuf
  __shared__ __align__(16) short bS[2*2*2*FBLK];   // LSTM2 state dbuf
  __shared__ float cS[64][16];                     // c1-final handoff A->B
  __shared__ float win_s[WIN][NB];
  __shared__ float Hlast[NB][68];
  __shared__ float fc1w_s[64*68];
  __shared__ float dval_s[NB];

  const int tid = threadIdx.x;
  const int wv8 = tid >> 6;          // 0..7
  const int wv  = wv8 & 3;           // role-local wave id 0..3
  const bool isA = (wv8 < 4);
  const int ln  = tid & 63;
  const int q   = ln >> 4;
  const int n   = ln & 15;
  const int bg0 = blockIdx.x * NB;
  const int u0  = 16*wv + 4*q;
  const int kt_  = u0 >> 5;
  const int q2_  = (u0 >> 3) & 3;
  const int jj0_ = u0 & 7;                          // {0,4}
  const int rdo  = q*FROW + n*8;                    // frag read offset
  const int wro  = q2_*FROW + n*8 + jj0_;           // frag write offset
  const int gwo  = kt_*512 + q2_*128 + n*8 + jj0_;  // hist write offset
  const int ro   = q*128 + n*8;                     // hist read offset
  short* __restrict__ hblk = hist + (size_t)blockIdx.x * WIN * 2048;

  for (int i = tid; i < WIN*NB; i += NT){ int t = i >> 4, b = i & 15; win_s[t][b] = x[(bg0 + b)*169 + t]; }
  for (int i = tid; i < 64*65; i += NT){ int j = i / 65, k = i % 65; fc1w_s[j*68 + k] = fc1w[i]; }
  if (tid < NB) dval_s[tid] = x[(bg0 + tid)*169 + 168];

  const float fc1b_r = fc1b[ln];
  const float fc2w_r = fc2w[ln];
  const float fc2b_r = fc2b[0];

  // FC head: all 8 waves, 2 batches each. Identical math to R5 per batch.
  auto fc_head = [&](int s){
    float o2[2];
    #pragma unroll
    for (int bi = 0; bi < 2; bi++){
      const int b = 2*wv8 + bi;
      float a1 = fc1b_r;
      #pragma unroll
      for (int k4 = 0; k4 < 16; k4++){
        const float* wp = &fc1w_s[ln*68 + k4*4];
        const float* hp = &Hlast[b][k4*4];
        a1 += wp[0]*hp[0] + wp[1]*hp[1] + wp[2]*hp[2] + wp[3]*hp[3];
      }
      a1 += dval_s[b] * fc1w_s[ln*68 + 64];
      float v = a1 * fc2w_r;
      #pragma unroll
      for (int off = 32; off > 0; off >>= 1) v += __shfl_xor(v, off);
      o2[bi] = v + fc2b_r;
    }
    if (ln == 0){
      #pragma unroll
      for (int bi = 0; bi < 2; bi++){
        const int b = 2*wv8 + bi;
        out[(bg0 + b)*24 + s] = o2[bi];
        win_s[s % WIN][b] = o2[bi];
      }
    }
  };

  if (isA){
    // =================== A-branch: LSTM1 producer ===================
    bf16x8 A1hi[4][2], A1lo[4][2], Ain1[4];
    f32x4 b1c[4];
    #pragma unroll
    for (int e = 0; e < 4; e++){
      const int ja = 64*e + 16*wv + n;
      #pragma unroll
      for (int kt = 0; kt < 2; kt++){
        const float* p = Whh1 + ja*64 + kt*32 + q*8;
        #pragma unroll
        for (int jj = 0; jj < 8; jj++){ short h,l; split_s(p[jj], h, l); A1hi[e][kt][jj] = h; A1lo[e][kt][jj] = l; }
      }
      bf16x8 ain = {0,0,0,0,0,0,0,0};
      if (q == 0){ short wh, wl; split_s(Wih1[ja], wh, wl); ain[0] = wh; ain[1] = wh; ain[2] = wl; }
      Ain1[e] = ain;
      const int jc = 64*e + u0;
      #pragma unroll
      for (int r = 0; r < 4; r++) b1c[e][r] = bih1[jc+r] + bhh1[jc+r];
    }
    float c1[4];

    auto lstm1 = [&](int rb, int wb, int slot, int t, bool first){
      f32x4 acc[4];
      bf16x8 bin = {0,0,0,0,0,0,0,0};
      { float xv = win_s[slot][n]; uint32_t xh, xl; split_t(xv, xh, xl);
        if (q == 0){ bin[0] = (short)xh; bin[1] = (short)xl; bin[2] = (short)xh; } }
      if (first){
        #pragma unroll
        for (int e = 0; e < 4; e++) acc[e] = mfma16(Ain1[e], bin, b1c[e]);
      } else {
        bf16x8 Bh0 = *(const bf16x8*)&aS[FB(rb,0,0)+rdo];
        bf16x8 Bl0 = *(const bf16x8*)&aS[FB(rb,1,0)+rdo];
        bf16x8 Bh1 = *(const bf16x8*)&aS[FB(rb,0,1)+rdo];
        bf16x8 Bl1 = *(const bf16x8*)&aS[FB(rb,1,1)+rdo];
        #pragma unroll
        for (int e = 0; e < 4; e++){
          f32x4 a = b1c[e];
          a = mfma16(A1hi[e][0], Bh0, a);
          a = mfma16(A1hi[e][0], Bl0, a);
          a = mfma16(A1lo[e][0], Bh0, a);
          a = mfma16(A1hi[e][1], Bh1, a);
          a = mfma16(A1hi[e][1], Bl1, a);
          a = mfma16(A1lo[e][1], Bh1, a);
          a = mfma16(Ain1[e], bin, a);
          acc[e] = a;
        }
      }
      float hn[4];
      lstm_epi(acc, c1, hn);
      uint32_t ph[4], pl[4];
      #pragma unroll
      for (int r = 0; r < 4; r++) split_t(hn[r], ph[r], pl[r]);
      *(uint2*)&aS[FB(wb,0,kt_)+wro] = make_uint2(ph[0] | (ph[1]<<16), ph[2] | (ph[3]<<16));
      *(uint2*)&aS[FB(wb,1,kt_)+wro] = make_uint2(pl[0] | (pl[1]<<16), pl[2] | (pl[3]<<16));
      uint32_t sh[4], sl[4];
      #pragma unroll
      for (int r = 0; r < 4; r++){ bool pos = hn[r] > 0.0f; sh[r] = pos ? ph[r] : 0u; sl[r] = pos ? pl[r] : 0u; }
      short* Hp = hblk + (size_t)t * 2048;
      *(uint2*)&Hp[gwo]        = make_uint2(sh[0] | (sh[1]<<16), sh[2] | (sh[3]<<16));
      *(uint2*)&Hp[1024 + gwo] = make_uint2(sl[0] | (sl[1]<<16), sl[2] | (sl[3]<<16));
    };

    // ---- sweep 0: A(0) alone. 168 barriers.
    #pragma unroll
    for (int r = 0; r < 4; r++) c1[r] = 0.0f;
    for (int t = 0; t < WIN; t++){
      __syncthreads();
      lstm1(t & 1, (t & 1) ^ 1, t, t, t == 0);
    }
    #pragma unroll
    for (int r = 0; r < 4; r++) cS[u0 + r][n] = c1[r];   // c1-final handoff

    // ---- fused sweeps sg=1..23. 170 barriers each.
    for (int sg = 1; sg < NSTEPS; sg++){
      #pragma unroll
      for (int r = 0; r < 4; r++) c1[r] = 0.0f;
      int slot = sg;
      __syncthreads();                       // t=0
      lstm1(0, 1, slot, 0, true);
      slot++;
      for (int t = 1; t < WIN-1; t++){
        __syncthreads();
        lstm1(t & 1, (t & 1) ^ 1, slot, t, false);
        slot++; if (slot == WIN) slot = 0;
      }
      __syncthreads();                       // (a): B does lstm2(167)
      __syncthreads();                       // (b): Hlast ready
      fc_head(sg - 1);
      __syncthreads();                       // (c): window updated
      lstm1(1, 0, slot, WIN-1, false);       // slot == sg-1, final h1 -> aS[0]
      #pragma unroll
      for (int r = 0; r < 4; r++) cS[u0 + r][n] = c1[r];
    }

    // ---- final sweep: B(23) alone. 169 barriers then FC.
    for (int i = 0; i < WIN + 1; i++) __syncthreads();
    fc_head(NSTEPS - 1);

  } else {
    // =================== B-branch: LSTM2 consumer ===================
    bf16x8 A2hi[4][4], A2lo[4][4];
    f32x4 b2c[4];
    #pragma unroll
    for (int e = 0; e < 4; e++){
      const int ja = 64*e + 16*wv + n;
      #pragma unroll
      for (int kt = 0; kt < 4; kt++){
        const float* p = (kt < 2 ? (Wih2 + ja*64 + kt*32) : (Whh2 + ja*64 + (kt-2)*32)) + q*8;
        #pragma unroll
        for (int jj = 0; jj < 8; jj++){ short h,l; split_s(p[jj], h, l); A2hi[e][kt][jj] = h; A2lo[e][kt][jj] = l; }
      }
      const int jc = 64*e + u0;
      #pragma unroll
      for (int r = 0; r < 4; r++) b2c[e][r] = bih2[jc+r] + bhh2[jc+r];
    }
    float c2[4];
    bf16x8 ch0, cl0, ch1, cl1, nh0, nl0, nh1, nl1;

    auto loadc = [&](int t){
      const short* Hp = hblk + (size_t)t * 2048;
      ch0 = *(const bf16x8*)&Hp[ro];
      cl0 = *(const bf16x8*)&Hp[1024 + ro];
      ch1 = *(const bf16x8*)&Hp[512 + ro];
      cl1 = *(const bf16x8*)&Hp[1536 + ro];
    };
    auto loadn = [&](int t){
      const short* Hp = hblk + (size_t)t * 2048;
      nh0 = *(const bf16x8*)&Hp[ro];
      nl0 = *(const bf16x8*)&Hp[1024 + ro];
      nh1 = *(const bf16x8*)&Hp[512 + ro];
      nl1 = *(const bf16x8*)&Hp[1536 + ro];
    };
    auto shift = [&](){ ch0 = nh0; cl0 = nl0; ch1 = nh1; cl1 = nl1; };

    auto lstm2 = [&](const short* Sr, int rb, short* Sw, int wb, bool last){
      bf16x8 L2h0 = *(const bf16x8*)&Sr[FB(rb,0,0)+rdo];
      bf16x8 L2l0 = *(const bf16x8*)&Sr[FB(rb,1,0)+rdo];
      bf16x8 L2h1 = *(const bf16x8*)&Sr[FB(rb,0,1)+rdo];
      bf16x8 L2l1 = *(const bf16x8*)&Sr[FB(rb,1,1)+rdo];
      f32x4 acc[4];
      #pragma unroll
      for (int e = 0; e < 4; e++){
        f32x4 a = b2c[e];
        a = mfma16(A2hi[e][0], ch0, a);
        a = mfma16(A2hi[e][0], cl0, a);
        a = mfma16(A2lo[e][0], ch0, a);
        a = mfma16(A2hi[e][1], ch1, a);
        a = mfma16(A2hi[e][1], cl1, a);
        a = mfma16(A2lo[e][1], ch1, a);
        a = mfma16(A2hi[e][2], L2h0, a);
        a = mfma16(A2hi[e][2], L2l0, a);
        a = mfma16(A2lo[e][2], L2h0, a);
        a = mfma16(A2hi[e][3], L2h1, a);
        a = mfma16(A2hi[e][3], L2l1, a);
        a = mfma16(A2lo[e][3], L2h1, a);
        acc[e] = a;
      }
      float hn[4];
      lstm_epi(acc, c2, hn);
      if (!last){
        uint32_t ph[4], pl[4];
        #pragma unroll
        for (int r = 0; r < 4; r++) split_t(hn[r], ph[r], pl[r]);
        *(uint2*)&Sw[FB(wb,0,kt_)+wro] = make_uint2(ph[0] | (ph[1]<<16), ph[2] | (ph[3]<<16));
        *(uint2*)&Sw[FB(wb,1,kt_)+wro] = make_uint2(pl[0] | (pl[1]<<16), pl[2] | (pl[3]<<16));
      } else {
        #pragma unroll
        for (int r = 0; r < 4; r++) Hlast[n][u0 + r] = fmaxf(hn[r], 0.0f);
      }
    };

    // ---- sweep 0: idle. 168 barriers.
    for (int i = 0; i < WIN; i++) __syncthreads();

    // ---- fused sweeps sg=1..23: B(sg-1). 170 barriers each.
    for (int sg = 1; sg < NSTEPS; sg++){
      loadc(0);
      loadn(1);
      __syncthreads();                       // t=0 (drains loads)
      #pragma unroll
      for (int r = 0; r < 4; r++) c2[r] = cS[u0 + r][n];
      lstm2(aS, 0, bS, 1, false);            // t=0: h2-init from aS[0]
      shift();
      for (int t = 1; t < WIN-1; t++){
        loadn(t + 1);
        __syncthreads();
        lstm2(bS, t & 1, bS, (t & 1) ^ 1, false);
        shift();
      }
      __syncthreads();                       // (a)
      lstm2(bS, 1, bS, 0, true);             // t=167 -> Hlast
      __syncthreads();                       // (b)
      fc_head(sg - 1);
      __syncthreads();                       // (c)
    }

    // ---- final sweep: B(23). 169 barriers then FC.
    {
      loadc(0);
      loadn(1);
      __syncthreads();
      #pragma unroll
      for (int r = 0; r < 4; r++) c2[r] = cS[u0 + r][n];
      lstm2(aS, 0, bS, 1, false);
      shift();
      for (int t = 1; t < WIN; t++){
        if (t < WIN-1) loadn(t + 1);
        __syncthreads();
        lstm2(bS, t & 1, bS, (t & 1) ^ 1, t == WIN-1);
        shift();
      }
      __syncthreads();
      fc_head(NSTEPS - 1);
    }
  }
}

// ============================================================================
// Fallback (no workspace): R4/R5 replay scheme, 256 threads. Safety only.
// ============================================================================
__global__ __launch_bounds__(256, 1) void lstm_fallback_kernel(
  const float* __restrict__ x,    const float* __restrict__ Wih1, const float* __restrict__ Whh1,
  const float* __restrict__ bih1, const float* __restrict__ bhh1,
  const float* __restrict__ Wih2, const float* __restrict__ Whh2,
  const float* __restrict__ bih2, const float* __restrict__ bhh2,
  const float* __restrict__ fc1w, const float* __restrict__ fc1b,
  const float* __restrict__ fc2w, const float* __restrict__ fc2b,
  float* __restrict__ out)
{
  __shared__ __align__(16) short aS[2*2*2*FBLK];
  __shared__ __align__(16) short r1f[2*2*2*FBLK];
  __shared__ __align__(16) short rlf[2*2*2*FBLK];
  __shared__ float win_s[WIN][NB];
  __shared__ float Hlast[NB][68];
  __shared__ float fc1w_s[64*68];
  __shared__ float dval_s[NB];

  const int tid = threadIdx.x;
  const int wv  = tid >> 6;
  const int ln  = tid & 63;
  const int q   = ln >> 4;
  const int n   = ln & 15;
  const int bg0 = blockIdx.x * NB;
  const int u0  = 16*wv + 4*q;
  const int kt_  = u0 >> 5;
  const int q2_  = (u0 >> 3) & 3;
  const int jj0_ = u0 & 7;
  const int rdo  = q*FROW + n*8;
  const int wro  = q2_*FROW + n*8 + jj0_;

  for (int i = tid; i < WIN*NB; i += 256){ int t = i >> 4, b = i & 15; win_s[t][b] = x[(bg0 + b)*169 + t]; }
  for (int i = tid; i < 64*65; i += 256){ int j = i / 65, k = i % 65; fc1w_s[j*68 + k] = fc1w[i]; }
  if (tid < NB) dval_s[tid] = x[(bg0 + tid)*169 + 168];

  const float fc1b_r = fc1b[ln];
  const float fc2w_r = fc2w[ln];
  const float fc2b_r = fc2b[0];

  bf16x8 A1hi[4][2], A1lo[4][2], Ain1[4];
  bf16x8 A2hi[4][4], A2lo[4][4];
  f32x4 b1c[4], b2c[4];
  #pragma unroll
  for (int e = 0; e < 4; e++){
    const int ja = 64*e + 16*wv + n;
    #pragma unroll
    for (int kt = 0; kt < 2; kt++){
      const float* p = Whh1 + ja*64 + kt*32 + q*8;
      #pragma unroll
      for (int jj = 0; jj < 8; jj++){ short h,l; split_s(p[jj], h, l); A1hi[e][kt][jj] = h; A1lo[e][kt][jj] = l; }
    }
    #pragma unroll
    for (int kt = 0; kt < 4; kt++){
      const float* p = (kt < 2 ? (Wih2 + ja*64 + kt*32) : (Whh2 + ja*64 + (kt-2)*32)) + q*8;
      #pragma unroll
      for (int jj = 0; jj < 8; jj++){ short h,l; split_s(p[jj], h, l); A2hi[e][kt][jj] = h; A2lo[e][kt][jj] = l; }
    }
    bf16x8 ain = {0,0,0,0,0,0,0,0};
    if (q == 0){ short wh, wl; split_s(Wih1[ja], wh, wl); ain[0] = wh; ain[1] = wh; ain[2] = wl; }
    Ain1[e] = ain;
    const int jc = 64*e + u0;
    #pragma unroll
    for (int r = 0; r < 4; r++){
      b1c[e][r] = bih1[jc+r] + bhh1[jc+r];
      b2c[e][r] = bih2[jc+r] + bhh2[jc+r];
    }
  }

  float c1[4], c2[4], c1r[4];

  auto lstm1_step = [&](short* S, float* cst, int rb, int wb, int slot, bool relu_out){
    bf16x8 Bh0 = *(const bf16x8*)&S[FB(rb,0,0)+rdo];
    bf16x8 Bl0 = *(const bf16x8*)&S[FB(rb,1,0)+rdo];
    bf16x8 Bh1 = *(const bf16x8*)&S[FB(rb,0,1)+rdo];
    bf16x8 Bl1 = *(const bf16x8*)&S[FB(rb,1,1)+rdo];
    bf16x8 bin = {0,0,0,0,0,0,0,0};
    { float xv = win_s[slot][n]; uint32_t xh, xl; split_t(xv, xh, xl);
      if (q == 0){ bin[0] = (short)xh; bin[1] = (short)xl; bin[2] = (short)xh; } }
    f32x4 acc[4];
    #pragma unroll
    for (int e = 0; e < 4; e++){
      f32x4 a = b1c[e];
      a = mfma16(A1hi[e][0], Bh0, a);
      a = mfma16(A1hi[e][0], Bl0, a);
      a = mfma16(A1lo[e][0], Bh0, a);
      a = mfma16(A1hi[e][1], Bh1, a);
      a = mfma16(A1hi[e][1], Bl1, a);
      a = mfma16(A1lo[e][1], Bh1, a);
      a = mfma16(Ain1[e], bin, a);
      acc[e] = a;
    }
    float hn[4];
    lstm_epi(acc, cst, hn);
    uint32_t ph[4], pl[4];
    #pragma unroll
    for (int r = 0; r < 4; r++) split_t(hn[r], ph[r], pl[r]);
    *(uint2*)&S[FB(wb,0,kt_)+wro] = make_uint2(ph[0] | (ph[1]<<16), ph[2] | (ph[3]<<16));
    *(uint2*)&S[FB(wb,1,kt_)+wro] = make_uint2(pl[0] | (pl[1]<<16), pl[2] | (pl[3]<<16));
    if (relu_out){
      uint32_t sh[4], sl[4];
      #pragma unroll
      for (int r = 0; r < 4; r++){ bool pos = hn[r] > 0.0f; sh[r] = pos ? ph[r] : 0u; sl[r] = pos ? pl[r] : 0u; }
      *(uint2*)&rlf[FB(rb,0,kt_)+wro] = make_uint2(sh[0] | (sh[1]<<16), sh[2] | (sh[3]<<16));
      *(uint2*)&rlf[FB(rb,1,kt_)+wro] = make_uint2(sl[0] | (sl[1]<<16), sl[2] | (sl[3]<<16));
    }
  };

  auto lstm2_core = [&](bf16x8 L1h0, bf16x8 L1l0, bf16x8 L1h1, bf16x8 L1l1,
                        int rbuf, int wbuf, bool last){
    bf16x8 L2h0 = *(const bf16x8*)&aS[FB(rbuf,0,0)+rdo];
    bf16x8 L2l0 = *(const bf16x8*)&aS[FB(rbuf,1,0)+rdo];
    bf16x8 L2h1 = *(const bf16x8*)&aS[FB(rbuf,0,1)+rdo];
    bf16x8 L2l1 = *(const bf16x8*)&aS[FB(rbuf,1,1)+rdo];
    f32x4 acc[4];
    #pragma unroll
    for (int e = 0; e < 4; e++){
      f32x4 a = b2c[e];
      a = mfma16(A2hi[e][0], L1h0, a);
      a = mfma16(A2hi[e][0], L1l0, a);
      a = mfma16(A2lo[e][0], L1h0, a);
      a = mfma16(A2hi[e][1], L1h1, a);
      a = mfma16(A2hi[e][1], L1l1, a);
      a = mfma16(A2lo[e][1], L1h1, a);
      a = mfma16(A2hi[e][2], L2h0, a);
      a = mfma16(A2hi[e][2], L2l0, a);
      a = mfma16(A2lo[e][2], L2h0, a);
      a = mfma16(A2hi[e][3], L2h1, a);
      a = mfma16(A2hi[e][3], L2l1, a);
      a = mfma16(A2lo[e][3], L2h1, a);
      acc[e] = a;
    }
    float hn[4];
    lstm_epi(acc, c2, hn);
    if (!last){
      uint32_t ph[4], pl[4];
      #pragma unroll
      for (int r = 0; r < 4; r++) split_t(hn[r], ph[r], pl[r]);
      *(uint2*)&aS[FB(wbuf,0,kt_)+wro] = make_uint2(ph[0] | (ph[1]<<16), ph[2] | (ph[3]<<16));
      *(uint2*)&aS[FB(wbuf,1,kt_)+wro] = make_uint2(pl[0] | (pl[1]<<16), pl[2] | (pl[3]<<16));
    } else {
      #pragma unroll
      for (int r = 0; r < 4; r++) Hlast[n][u0 + r] = fmaxf(hn[r], 0.0f);
    }
  };

  for (int s = 0; s < NSTEPS; s++){
    { int* p = (int*)&aS[0];
      for (int i = tid; i < BUF_INTS; i += 256) p[i] = 0; }
    #pragma unroll
    for (int r = 0; r < 4; r++) c1[r] = 0.0f;
    int slot = s;
    for (int t = 0; t < WIN; t++){
      __syncthreads();
      lstm1_step(aS, c1, t & 1, (t & 1) ^ 1, slot, false);
      slot++; if (slot == WIN) slot = 0;
    }
    #pragma unroll
    for (int r = 0; r < 4; r++){ c2[r] = c1[r]; c1r[r] = 0.0f; }
    { int* p = (int*)&r1f[0];
      for (int i = tid; i < BUF_INTS; i += 256) p[i] = 0; }
    slot = s;
    __syncthreads();
    lstm1_step(r1f, c1r, 0, 1, slot, true);
    slot++;
    for (int i = 1; i < WIN; i++){
      __syncthreads();
      const int rb = i & 1, wb = rb ^ 1;
      lstm1_step(r1f, c1r, rb, wb, slot, true);
      bf16x8 L1h0 = *(const bf16x8*)&rlf[FB(wb,0,0)+rdo];
      bf16x8 L1l0 = *(const bf16x8*)&rlf[FB(wb,1,0)+rdo];
      bf16x8 L1h1 = *(const bf16x8*)&rlf[FB(wb,0,1)+rdo];
      bf16x8 L1l1 = *(const bf16x8*)&rlf[FB(wb,1,1)+rdo];
      lstm2_core(L1h0, L1l0, L1h1, L1l1, wb, rb, false);
      slot++; if (slot == WIN) slot = 0;
    }
    __syncthreads();
    {
      const int rb = (WIN - 1) & 1;
      bf16x8 L1h0 = *(const bf16x8*)&rlf[FB(rb,0,0)+rdo];
      bf16x8 L1l0 = *(const bf16x8*)&rlf[FB(rb,1,0)+rdo];
      bf16x8 L1h1 = *(const bf16x8*)&rlf[FB(rb,0,1)+rdo];
      bf16x8 L1l1 = *(const bf16x8*)&rlf[FB(rb,1,1)+rdo];
      lstm2_core(L1h0, L1l0, L1h1, L1l1, rb, 0, true);
    }
    __syncthreads();
    {
      float o4[4];
      #pragma unroll
      for (int bi = 0; bi < 4; bi++){
        const int b = 4*wv + bi;
        float a1 = fc1b_r;
        #pragma unroll
        for (int k4 = 0; k4 < 16; k4++){
          const float* wp = &fc1w_s[ln*68 + k4*4];
          const float* hp = &Hlast[b][k4*4];
          a1 += wp[0]*hp[0] + wp[1]*hp[1] + wp[2]*hp[2] + wp[3]*hp[3];
        }
        a1 += dval_s[b] * fc1w_s[ln*68 + 64];
        float v = a1 * fc2w_r;
        #pragma unroll
        for (int off = 32; off > 0; off >>= 1) v += __shfl_xor(v, off);
        o4[bi] = v + fc2b_r;
      }
      if (ln == 0){
        #pragma unroll
        for (int bi = 0; bi < 4; bi++){
          const int b = 4*wv + bi;
          out[(bg0 + b)*24 + s] = o4[bi];
          win_s[s % WIN][b] = o4[bi];
        }
      }
    }
  }
}

extern "C" void kernel_launch(void* const* d_in, const int* in_sizes, int n_in,
                              void* d_out, int out_size, void* d_ws, size_t ws_size,
                              hipStream_t stream) {
  (void)in_sizes; (void)n_in; (void)out_size;
  const size_t need = (size_t)NBLK * WIN * 2048 * sizeof(short);   // ~168 MB
  if (ws_size >= need){
    lstm_fused_kernel<<<dim3(NBLK), dim3(NT), 0, stream>>>(
        (const float*)d_in[0], (const float*)d_in[1], (const float*)d_in[2],
        (const float*)d_in[3], (const float*)d_in[4], (const float*)d_in[5],
        (const float*)d_in[6], (const float*)d_in[7], (const float*)d_in[8],
        (const float*)d_in[9], (const float*)d_in[10], (const float*)d_in[11],
        (const float*)d_in[12], (float*)d_out, (short*)d_ws);
  } else {
    lstm_fallback_kernel<<<dim3(NBLK), dim3(256), 0, stream>>>(
        (const float*)d_in[0], (const float*)d_in[1], (const float*)d_in[2],
        (const float*)d_in[3], (const float*)d_in[4], (const float*)d_in[5],
        (const float*)d_in[6], (const float*)d_in[7], (const float*)d_in[8],
        (const float*)d_in[9], (const float*)d_in[10], (const float*)d_in[11],
        (const float*)d_in[12], (float*)d_out);
  }
}